// Round 9
// baseline (543.867 us; speedup 1.0000x reference)
//
#include <hip/hip_runtime.h>
#include <stdint.h>

typedef __attribute__((ext_vector_type(8))) short bf16x8;
typedef __attribute__((ext_vector_type(4))) float f32x4;

#define BN 1024      // dst nodes per bucket (power of 2)
#define BNSHIFT 10
#define MAXNB 512    // supports N up to 512*1024
#define PTI 8192     // edges per partition tile
#define PTHREADS 512
#define EPT (PTI / PTHREADS)
#define SL 16        // source slices per node (sorted ascending -> L2 sweep)
#define SSH 15       // slice = src >> SSH  (4.2 MB table slice ~ XCD L2)
#define BINS (BN * SL)

static __device__ __forceinline__ float b2f_lo(uint32_t w) {
  union { uint32_t u; float f; } c; c.u = w << 16; return c.f;
}
static __device__ __forceinline__ float b2f_hi(uint32_t w) {
  union { uint32_t u; float f; } c; c.u = w & 0xffff0000u; return c.f;
}
static __device__ __forceinline__ uint16_t f2b(float f) {
  union { float f; uint32_t u; } c; c.f = f;
  return (uint16_t)((c.u + 0x7fffu + ((c.u >> 16) & 1u)) >> 16);
}
static __device__ __forceinline__ void acc8(float* s, uint4 v) {
  s[0] += b2f_lo(v.x); s[1] += b2f_hi(v.x);
  s[2] += b2f_lo(v.y); s[3] += b2f_hi(v.y);
  s[4] += b2f_lo(v.z); s[5] += b2f_hi(v.z);
  s[6] += b2f_lo(v.w); s[7] += b2f_hi(v.w);
}

// ---------------- fp32 -> bf16 embedding conversion (into xb buffer) --------
__global__ __launch_bounds__(256) void convert_kernel(
    const float* __restrict__ emb_pl, const float* __restrict__ emb_tr,
    uint16_t* __restrict__ xb, int NP, int N) {
  long g = (long)blockIdx.x * 256 + threadIdx.x;
  long base8 = g * 8;
  long total = (long)N * 64;
  if (base8 >= total) return;
  long plEnd = (long)NP * 64;  // divisible by 8, no straddle
  const float* src = (base8 < plEnd) ? (emb_pl + base8) : (emb_tr + (base8 - plEnd));
  f32x4 a = *(const f32x4*)src;
  f32x4 b = *(const f32x4*)(src + 4);
  union { uint16_t h[8]; uint4 v; } o;
  o.h[0] = f2b(a.x); o.h[1] = f2b(a.y); o.h[2] = f2b(a.z); o.h[3] = f2b(a.w);
  o.h[4] = f2b(b.x); o.h[5] = f2b(b.y); o.h[6] = f2b(b.z); o.h[7] = f2b(b.w);
  *(uint4*)(xb + base8) = o.v;
}

// ---------------- bucket histogram over dst (both relations) ----------------
__global__ __launch_bounds__(256) void bucket_hist_kernel(
    const int* __restrict__ pt_dst, const int* __restrict__ tp_dst,
    int* __restrict__ bucketCount, int E, int NP, int NB) {
  extern __shared__ int hist[];
  int t = threadIdx.x;
  for (int b = t; b < NB; b += 256) hist[b] = 0;
  __syncthreads();
  long total = 2L * E;
  long stride = (long)gridDim.x * 256;
  for (long e = (long)blockIdx.x * 256 + t; e < total; e += stride) {
    int dstG = (e < E) ? (NP + pt_dst[e]) : tp_dst[e - E];
    atomicAdd(&hist[dstG >> BNSHIFT], 1);
  }
  __syncthreads();
  for (int b = t; b < NB; b += 256) {
    int h = hist[b];
    if (h > 0) atomicAdd(&bucketCount[b], h);
  }
}

// ---------------- exclusive scan of counts (1 block, generic NB) ------------
__global__ __launch_bounds__(1024) void bucket_scan_kernel(
    const int* __restrict__ bucketCount, int* __restrict__ bucketStart,
    int* __restrict__ gCursor, int NB) {
  __shared__ int s[1024];
  int t = threadIdx.x;
  int K = (NB + 1023) >> 10;
  int b0 = t * K;
  int local = 0;
  for (int j = 0; j < K; ++j) {
    int b = b0 + j;
    if (b < NB) local += bucketCount[b];
  }
  int acc = local;
  s[t] = local;
  __syncthreads();
  for (int off = 1; off < 1024; off <<= 1) {
    int u = (t >= off) ? s[t - off] : 0;
    __syncthreads();
    acc += u;
    s[t] = acc;
    __syncthreads();
  }
  int run = acc - local;  // exclusive prefix of this thread's chunk
  for (int j = 0; j < K; ++j) {
    int b = b0 + j;
    if (b < NB) {
      bucketStart[b] = run;
      gCursor[b] = run;
      run += bucketCount[b];
    }
  }
}

// ---------------- partition: LDS tile-sort, then coalesced write ------------
__global__ __launch_bounds__(PTHREADS) void partition_kernel(
    const int* __restrict__ pt_src, const int* __restrict__ pt_dst,
    const int* __restrict__ tp_src, const int* __restrict__ tp_dst,
    int* __restrict__ gCursor, uint32_t* __restrict__ pk,
    int E, int NP, int NB) {
  __shared__ uint64_t buf[PTI];    // 64 KB sorted staging
  __shared__ int hist[MAXNB];
  __shared__ int lstart[MAXNB];
  __shared__ int gbase[MAXNB];
  __shared__ int cur[MAXNB];
  __shared__ int sc[PTHREADS];
  int t = threadIdx.x;
  long total = 2L * E;
  long e0 = (long)blockIdx.x * PTI;
  long rem = total - e0;
  int cnt = (rem < (long)PTI) ? (int)rem : PTI;

  for (int j = t; j < NB; j += PTHREADS) hist[j] = 0;
  __syncthreads();

  int bj[EPT];
  uint32_t pkj[EPT];
#pragma unroll
  for (int j = 0; j < EPT; ++j) {
    int i = j * PTHREADS + t;
    bj[j] = -1;
    if (i < cnt) {
      long e = e0 + i;
      int dstG, src;
      if (e < E) {
        dstG = NP + __builtin_nontemporal_load(&pt_dst[e]);
        src = __builtin_nontemporal_load(&pt_src[e]);
      } else {
        dstG = __builtin_nontemporal_load(&tp_dst[e - E]);
        src = NP + __builtin_nontemporal_load(&tp_src[e - E]);
      }
      int b = dstG >> BNSHIFT;
      bj[j] = b;
      pkj[j] = ((uint32_t)(dstG & (BN - 1)) << 20) | (uint32_t)src;
      atomicAdd(&hist[b], 1);
    }
  }
  __syncthreads();

  // inclusive scan of hist[0..NB) across PTHREADS slots (NB <= PTHREADS)
  int h = (t < NB) ? hist[t] : 0;
  int acc = h;
  sc[t] = h;
  __syncthreads();
  for (int off = 1; off < PTHREADS; off <<= 1) {
    int u = (t >= off) ? sc[t - off] : 0;
    __syncthreads();
    acc += u;
    sc[t] = acc;
    __syncthreads();
  }
  if (t < NB) {
    int ls = acc - h;  // exclusive prefix
    lstart[t] = ls;
    cur[t] = ls;
    gbase[t] = (h > 0) ? atomicAdd(&gCursor[t], h) : 0;
  }
  __syncthreads();

  // scatter into LDS, sorted by bucket; attach final global position
#pragma unroll
  for (int j = 0; j < EPT; ++j) {
    int b = bj[j];
    if (b >= 0) {
      int pos = atomicAdd(&cur[b], 1);
      int gpos = gbase[b] + (pos - lstart[b]);
      buf[pos] = ((uint64_t)(uint32_t)gpos << 32) | (uint64_t)pkj[j];
    }
  }
  __syncthreads();

  // coalesced drain: consecutive lanes hit consecutive slots within runs
  for (int i = t; i < cnt; i += PTHREADS) {
    uint64_t e = buf[i];
    pk[(uint32_t)(e >> 32)] = (uint32_t)e;
  }
}

// ---------------- per-bucket counting sort -> node-grouped CSR --------------
// Sort key widened to (dl, src>>SSH): within each node, cols come out grouped
// by ascending source slice. All concurrent pull waves then sweep the gather
// table low->high in rough lockstep, shrinking the live L2 working set from
// the whole 38 MB table to a ~4 MB slice (per-XCD L2 size).
__global__ __launch_bounds__(512) void local_csr_kernel(
    const int* __restrict__ bucketStart, const int* __restrict__ bucketCount,
    const uint32_t* __restrict__ pk, int* __restrict__ rowptr,
    int* __restrict__ col, int N, int TEtotal) {
  __shared__ int hist[BINS];   // 64 KB: counts -> exclusive prefixes -> cursors
  __shared__ int ssum[512];
  int t = threadIdx.x;
  int b = blockIdx.x;
  for (int j = t; j < BINS; j += 512) hist[j] = 0;
  __syncthreads();
  int beg = bucketStart[b], num = bucketCount[b];
  for (int i = t; i < num; i += 512) {
    uint32_t w = pk[beg + i];
    int bin = (int)(((w >> 20) << 4) | ((w & 0xFFFFFu) >> SSH));
    atomicAdd(&hist[bin], 1);
  }
  __syncthreads();
  // scan 16384 bins: 32 serial per thread + 512-wide block scan
  int b0 = t * 32;  // covers dl = 2t, 2t+1 (16 slice bins each)
  int local = 0;
#pragma unroll
  for (int j = 0; j < 32; ++j) local += hist[b0 + j];
  int acc = local;
  ssum[t] = local;
  __syncthreads();
  for (int off = 1; off < 512; off <<= 1) {
    int u = (t >= off) ? ssum[t - off] : 0;
    __syncthreads();
    acc += u;
    ssum[t] = acc;
    __syncthreads();
  }
  int run = acc - local;  // exclusive prefix of this thread's 32 bins
  // rewrite bins in place to exclusive prefixes; rowptr at (dl,0) boundaries
  int node0 = (b << BNSHIFT) + t * 2;
  if (node0 < N) rowptr[node0] = beg + run;
#pragma unroll
  for (int j = 0; j < 32; ++j) {
    int h = hist[b0 + j];
    hist[b0 + j] = run;
    run += h;
    if (j == 15 && node0 + 1 < N) rowptr[node0 + 1] = beg + run;
  }
  __syncthreads();
  for (int i = t; i < num; i += 512) {
    uint32_t w = pk[beg + i];
    int bin = (int)(((w >> 20) << 4) | ((w & 0xFFFFFu) >> SSH));
    int pos = atomicAdd(&hist[bin], 1);
    col[beg + pos] = (int)(w & 0xFFFFFu);
  }
  if (b == 0 && t == 0) rowptr[N] = TEtotal;
}

// ---------------- pull aggregation: agg[n] = bf16(mean of src rows) ---------
// 8 lanes per node (8 nodes/wave), lane handles 8 dims via one uint4 (16 B).
// Natural node order; cols per node are source-slice-sorted (L2 sweep).
__global__ __launch_bounds__(256) void pull_kernel(
    const int* __restrict__ rowptr, const int* __restrict__ col,
    const uint16_t* __restrict__ base, uint16_t* __restrict__ agg, int N) {
  int node = blockIdx.x * 32 + (threadIdx.x >> 3);
  int c = threadIdx.x & 7;  // dims 8c..8c+7
  if (node >= N) return;
  int beg = rowptr[node], end = rowptr[node + 1];
  float s[8] = {0, 0, 0, 0, 0, 0, 0, 0};
  const uint16_t* bp = base + c * 8;
  int i = beg;
  for (; i + 4 <= end; i += 4) {
    int c0 = col[i], c1 = col[i + 1], c2 = col[i + 2], c3 = col[i + 3];
    uint4 v0 = *(const uint4*)(bp + (size_t)c0 * 64);
    uint4 v1 = *(const uint4*)(bp + (size_t)c1 * 64);
    uint4 v2 = *(const uint4*)(bp + (size_t)c2 * 64);
    uint4 v3 = *(const uint4*)(bp + (size_t)c3 * 64);
    acc8(s, v0); acc8(s, v1); acc8(s, v2); acc8(s, v3);
  }
  for (; i < end; ++i)
    acc8(s, *(const uint4*)(bp + (size_t)col[i] * 64));
  int deg = end - beg;
  float inv = 1.0f / (float)(deg > 1 ? deg : 1);
  union { uint16_t h[8]; uint4 v; } o;
#pragma unroll
  for (int j = 0; j < 8; ++j) o.h[j] = f2b(s[j] * inv);
  *(uint4*)(agg + (size_t)node * 64 + c * 8) = o.v;
}

// ---------------- fused transform: xout = relu(x@Wroot + agg@Wrel + b) ------
// FUSE=true (layer 1): writes S = emb + x + relu(...) instead of x2, killing
// the separate sum pass.
template <bool FUSE>
__global__ __launch_bounds__(256) void transform_kernel(
    const uint16_t* __restrict__ xpl, const uint16_t* __restrict__ xtr,
    const uint16_t* __restrict__ agg,
    const float* __restrict__ Wroot,
    const float* __restrict__ WrelP, const float* __restrict__ WrelT,
    const float* __restrict__ biasrow,
    const float* __restrict__ embP, const float* __restrict__ embT,
    uint16_t* __restrict__ xout, int NP, int NT, int BP) {
  int wave = threadIdx.x >> 6;
  int lane = threadIdx.x & 63;
  int m = lane & 15, q = lane >> 4;

  int wl, nw, ntiles, nodeBase;
  const uint16_t* xbase;
  const float* Wrel;
  const float* embBase;
  if ((int)blockIdx.x < BP) {
    wl = blockIdx.x * 4 + wave; nw = BP * 4; ntiles = NP / 16;
    xbase = xpl; Wrel = WrelP; nodeBase = 0; embBase = embP;
  } else {
    wl = (blockIdx.x - BP) * 4 + wave; nw = (gridDim.x - BP) * 4; ntiles = NT / 16;
    xbase = xtr; Wrel = WrelT; nodeBase = NP; embBase = embT;
  }

  // B fragments: B[k][n], lane n=16*ct+m, elems k=32*kc+8*q+i
  bf16x8 br[2][4], bl[2][4];
  for (int kc = 0; kc < 2; ++kc)
    for (int ct = 0; ct < 4; ++ct) {
      int n = 16 * ct + m;
      int k0 = 32 * kc + 8 * q;
      bf16x8 t0, t1;
      for (int i = 0; i < 8; ++i) {
        t0[i] = (short)f2b(Wroot[(size_t)(k0 + i) * 64 + n]);
        t1[i] = (short)f2b(Wrel[(size_t)(k0 + i) * 64 + n]);
      }
      br[kc][ct] = t0;
      bl[kc][ct] = t1;
    }
  float bv[4];
  for (int ct = 0; ct < 4; ++ct) bv[ct] = biasrow[16 * ct + m];

  for (int t = wl; t < ntiles; t += nw) {
    int rowLocal = t * 16 + m;  // A row: m = lane&15
    int nodeG = nodeBase + rowLocal;
    const uint16_t* xrow = xbase + (size_t)rowLocal * 64;
    bf16x8 ax0 = *(const bf16x8*)(xrow + 8 * q);
    bf16x8 ax1 = *(const bf16x8*)(xrow + 32 + 8 * q);

    const uint16_t* arow = agg + (size_t)nodeG * 64;
    bf16x8 aa0 = *(const bf16x8*)(arow + 8 * q);
    bf16x8 aa1 = *(const bf16x8*)(arow + 32 + 8 * q);

    f32x4 acc[4];
#pragma unroll
    for (int ct = 0; ct < 4; ++ct) acc[ct] = (f32x4){bv[ct], bv[ct], bv[ct], bv[ct]};
#pragma unroll
    for (int ct = 0; ct < 4; ++ct) {
      acc[ct] = __builtin_amdgcn_mfma_f32_16x16x32_bf16(ax0, br[0][ct], acc[ct], 0, 0, 0);
      acc[ct] = __builtin_amdgcn_mfma_f32_16x16x32_bf16(ax1, br[1][ct], acc[ct], 0, 0, 0);
      acc[ct] = __builtin_amdgcn_mfma_f32_16x16x32_bf16(aa0, bl[0][ct], acc[ct], 0, 0, 0);
      acc[ct] = __builtin_amdgcn_mfma_f32_16x16x32_bf16(aa1, bl[1][ct], acc[ct], 0, 0, 0);
    }
    // D: row = 4*q + r, col = 16*ct + m
    int nodeRow0 = nodeBase + t * 16;
    int localRow0 = t * 16;
#pragma unroll
    for (int ct = 0; ct < 4; ++ct)
#pragma unroll
      for (int r = 0; r < 4; ++r) {
        float v = acc[ct][r];
        v = v > 0.0f ? v : 0.0f;
        int colIdx = 16 * ct + m;
        size_t go = (size_t)(nodeRow0 + 4 * q + r) * 64 + colIdx;
        if (FUSE) {
          size_t lo = (size_t)(localRow0 + 4 * q + r) * 64 + colIdx;
          float e = embBase[lo];
          float x1f = b2f_lo((uint32_t)xbase[lo]);
          xout[go] = f2b(e + x1f + v);
        } else {
          xout[go] = f2b(v);
        }
      }
  }
}

// ---------------- link scores: (1/9) * dot(S_p, S_t) ------------------------
// 8 lanes per pair, 8 dims each via uint4 (16 B).
__global__ void score_kernel(const int* __restrict__ ell_pl,
                             const int* __restrict__ ell_tr,
                             const uint16_t* __restrict__ S,
                             float* __restrict__ out, int EP, int NP) {
  long g = (long)blockIdx.x * blockDim.x + threadIdx.x;
  long pair = g >> 3;
  int c = (int)(g & 7);
  if (pair >= EP) return;
  int p = __builtin_nontemporal_load(&ell_pl[pair]);
  int t = __builtin_nontemporal_load(&ell_tr[pair]);
  uint4 vp = *(const uint4*)(S + (size_t)p * 64 + c * 8);
  uint4 vt = *(const uint4*)(S + (size_t)(NP + t) * 64 + c * 8);
  float partial = b2f_lo(vp.x) * b2f_lo(vt.x) + b2f_hi(vp.x) * b2f_hi(vt.x)
                + b2f_lo(vp.y) * b2f_lo(vt.y) + b2f_hi(vp.y) * b2f_hi(vt.y)
                + b2f_lo(vp.z) * b2f_lo(vt.z) + b2f_hi(vp.z) * b2f_hi(vt.z)
                + b2f_lo(vp.w) * b2f_lo(vt.w) + b2f_hi(vp.w) * b2f_hi(vt.w);
  partial += __shfl_xor(partial, 1);
  partial += __shfl_xor(partial, 2);
  partial += __shfl_xor(partial, 4);
  if (c == 0) __builtin_nontemporal_store(partial * (1.0f / 9.0f), &out[pair]);
}

extern "C" void kernel_launch(void* const* d_in, const int* in_sizes, int n_in,
                              void* d_out, int out_size, void* d_ws, size_t ws_size,
                              hipStream_t stream) {
  const float* emb_pl = (const float*)d_in[0];
  const float* emb_tr = (const float*)d_in[1];
  const float* W_rel = (const float*)d_in[2];   // [L,2,64,64] f32
  const float* W_root = (const float*)d_in[3];  // [L,64,64] f32
  const float* bias = (const float*)d_in[4];    // [L,64] f32
  const int* pt_src = (const int*)d_in[7];
  const int* pt_dst = (const int*)d_in[8];
  const int* tp_src = (const int*)d_in[9];
  const int* tp_dst = (const int*)d_in[10];
  const int* ell_pl = (const int*)d_in[11];
  const int* ell_tr = (const int*)d_in[12];
  float* out = (float*)d_out;

  const int NP = in_sizes[5];
  const int NT = in_sizes[6];
  const int E = in_sizes[7];
  const int EP = in_sizes[11];
  const int N = NP + NT;
  const long TE = 2L * E;
  const int NB = (N + BN - 1) / BN;

  char* ws = (char*)d_ws;
  size_t off = 0;
  uint16_t* agg = (uint16_t*)(ws + off); off += (size_t)N * 64 * 2;   // bf16
  uint16_t* x1  = (uint16_t*)(ws + off); off += (size_t)N * 64 * 2;   // bf16
  uint16_t* xb0 = (uint16_t*)(ws + off); off += (size_t)N * 64 * 2;   // bf16 emb copy
  uint16_t* S   = (uint16_t*)(ws + off); off += (size_t)N * 64 * 2;   // node sums
  uint32_t* pk  = (uint32_t*)(ws + off); off += (size_t)TE * 4;
  int* col      = (int*)(ws + off);      off += (size_t)TE * 4;
  int* rowptr   = (int*)(ws + off);      off += (size_t)(N + 1) * 4;
  int* bucketCount = (int*)(ws + off);   off += (size_t)NB * 4;
  int* bucketStart = (int*)(ws + off);   off += (size_t)NB * 4;
  int* gCursor     = (int*)(ws + off);   off += (size_t)NB * 4;

  const int TB = 256;
  long cvt = ((long)N * 64 / 8 + TB - 1) / TB;
  int pullBlocks = (N + 31) / 32;
  int scoreBlocks = (int)(((long)EP * 8 + TB - 1) / TB);
  int partBlocks = (int)((TE + PTI - 1) / PTI);
  const int BP = 256, GT = 1024;  // transform grid split

  // ---- bf16 embedding copy (used by pull0 + transform0) ----
  convert_kernel<<<(int)cvt, TB, 0, stream>>>(emb_pl, emb_tr, xb0, NP, N);

  // ---- bucket build (once; reused by both layers) ----
  hipMemsetAsync(bucketCount, 0, (size_t)NB * 4, stream);
  bucket_hist_kernel<<<128, TB, NB * 4, stream>>>(pt_dst, tp_dst, bucketCount,
                                                  E, NP, NB);
  bucket_scan_kernel<<<1, 1024, 0, stream>>>(bucketCount, bucketStart, gCursor, NB);
  partition_kernel<<<partBlocks, PTHREADS, 0, stream>>>(
      pt_src, pt_dst, tp_src, tp_dst, gCursor, pk, E, NP, NB);
  local_csr_kernel<<<NB, 512, 0, stream>>>(bucketStart, bucketCount, pk,
                                           rowptr, col, N, (int)TE);

  // ---- layer 0 (x = bf16 embedding copy) ----
  pull_kernel<<<pullBlocks, TB, 0, stream>>>(rowptr, col, xb0, agg, N);
  transform_kernel<false><<<GT, TB, 0, stream>>>(
      xb0, xb0 + (size_t)NP * 64, agg, W_root + 0 * 4096, W_rel + 1 * 4096,
      W_rel + 0 * 4096, bias + 0, nullptr, nullptr, x1, NP, NT, BP);

  // ---- layer 1 (x = x1); epilogue fuses S = emb + x1 + relu(h2) ----
  pull_kernel<<<pullBlocks, TB, 0, stream>>>(rowptr, col, x1, agg, N);
  transform_kernel<true><<<GT, TB, 0, stream>>>(
      x1, x1 + (size_t)NP * 64, agg, W_root + 1 * 4096, W_rel + 3 * 4096,
      W_rel + 2 * 4096, bias + 64, emb_pl, emb_tr, S, NP, NT, BP);

  // ---- link scores ----
  score_kernel<<<scoreBlocks, TB, 0, stream>>>(ell_pl, ell_tr, S, out, EP, NP);
}

// Round 10
// 536.446 us; speedup vs baseline: 1.0138x; 1.0138x over previous
//
#include <hip/hip_runtime.h>
#include <stdint.h>

typedef __attribute__((ext_vector_type(8))) short bf16x8;
typedef __attribute__((ext_vector_type(4))) float f32x4;

#define BN 1024      // dst nodes per bucket (power of 2)
#define BNSHIFT 10
#define MAXNB 512    // supports N up to 512*1024
#define PTI 8192     // edges per partition tile
#define PTHREADS 1024
#define EPT (PTI / PTHREADS)   // 8
#define SL 16        // source slices per node (sorted ascending -> L2 sweep)
#define SSH 15       // slice = src >> SSH
#define BINS (BN * SL)

static __device__ __forceinline__ float b2f_lo(uint32_t w) {
  union { uint32_t u; float f; } c; c.u = w << 16; return c.f;
}
static __device__ __forceinline__ float b2f_hi(uint32_t w) {
  union { uint32_t u; float f; } c; c.u = w & 0xffff0000u; return c.f;
}
static __device__ __forceinline__ uint16_t f2b(float f) {
  union { float f; uint32_t u; } c; c.f = f;
  return (uint16_t)((c.u + 0x7fffu + ((c.u >> 16) & 1u)) >> 16);
}
static __device__ __forceinline__ void acc8(float* s, uint4 v) {
  s[0] += b2f_lo(v.x); s[1] += b2f_hi(v.x);
  s[2] += b2f_lo(v.y); s[3] += b2f_hi(v.y);
  s[4] += b2f_lo(v.z); s[5] += b2f_hi(v.z);
  s[6] += b2f_lo(v.w); s[7] += b2f_hi(v.w);
}

// ---------------- fp32 -> bf16 embedding conversion (into xb buffer) --------
__global__ __launch_bounds__(256) void convert_kernel(
    const float* __restrict__ emb_pl, const float* __restrict__ emb_tr,
    uint16_t* __restrict__ xb, int NP, int N) {
  long g = (long)blockIdx.x * 256 + threadIdx.x;
  long base8 = g * 8;
  long total = (long)N * 64;
  if (base8 >= total) return;
  long plEnd = (long)NP * 64;  // divisible by 8, no straddle
  const float* src = (base8 < plEnd) ? (emb_pl + base8) : (emb_tr + (base8 - plEnd));
  f32x4 a = *(const f32x4*)src;
  f32x4 b = *(const f32x4*)(src + 4);
  union { uint16_t h[8]; uint4 v; } o;
  o.h[0] = f2b(a.x); o.h[1] = f2b(a.y); o.h[2] = f2b(a.z); o.h[3] = f2b(a.w);
  o.h[4] = f2b(b.x); o.h[5] = f2b(b.y); o.h[6] = f2b(b.z); o.h[7] = f2b(b.w);
  *(uint4*)(xb + base8) = o.v;
}

// ---------------- bucket histogram over dst (both relations) ----------------
__global__ __launch_bounds__(256) void bucket_hist_kernel(
    const int* __restrict__ pt_dst, const int* __restrict__ tp_dst,
    int* __restrict__ bucketCount, int E, int NP, int NB) {
  extern __shared__ int hist[];
  int t = threadIdx.x;
  for (int b = t; b < NB; b += 256) hist[b] = 0;
  __syncthreads();
  long total = 2L * E;
  long stride = (long)gridDim.x * 256;
  for (long e = (long)blockIdx.x * 256 + t; e < total; e += stride) {
    int dstG = (e < E) ? (NP + pt_dst[e]) : tp_dst[e - E];
    atomicAdd(&hist[dstG >> BNSHIFT], 1);
  }
  __syncthreads();
  for (int b = t; b < NB; b += 256) {
    int h = hist[b];
    if (h > 0) atomicAdd(&bucketCount[b], h);
  }
}

// ---------------- exclusive scan of counts (1 block, generic NB) ------------
__global__ __launch_bounds__(1024) void bucket_scan_kernel(
    const int* __restrict__ bucketCount, int* __restrict__ bucketStart,
    int* __restrict__ gCursor, int NB) {
  __shared__ int s[1024];
  int t = threadIdx.x;
  int K = (NB + 1023) >> 10;
  int b0 = t * K;
  int local = 0;
  for (int j = 0; j < K; ++j) {
    int b = b0 + j;
    if (b < NB) local += bucketCount[b];
  }
  int acc = local;
  s[t] = local;
  __syncthreads();
  for (int off = 1; off < 1024; off <<= 1) {
    int u = (t >= off) ? s[t - off] : 0;
    __syncthreads();
    acc += u;
    s[t] = acc;
    __syncthreads();
  }
  int run = acc - local;  // exclusive prefix of this thread's chunk
  for (int j = 0; j < K; ++j) {
    int b = b0 + j;
    if (b < NB) {
      bucketStart[b] = run;
      gCursor[b] = run;
      run += bucketCount[b];
    }
  }
}

// ---------------- partition: LDS tile-sort, then coalesced write ------------
// 1024 threads, EPT=8: 16 waves/block x 2 blocks/CU (74 KB LDS) = 100% occ.
__global__ __launch_bounds__(PTHREADS) void partition_kernel(
    const int* __restrict__ pt_src, const int* __restrict__ pt_dst,
    const int* __restrict__ tp_src, const int* __restrict__ tp_dst,
    int* __restrict__ gCursor, uint32_t* __restrict__ pk,
    int E, int NP, int NB) {
  __shared__ uint64_t buf[PTI];    // 64 KB sorted staging
  __shared__ int hist[MAXNB];
  __shared__ int lstart[MAXNB];
  __shared__ int gbase[MAXNB];
  __shared__ int cur[MAXNB];
  __shared__ int sc[PTHREADS];
  int t = threadIdx.x;
  long total = 2L * E;
  long e0 = (long)blockIdx.x * PTI;
  long rem = total - e0;
  int cnt = (rem < (long)PTI) ? (int)rem : PTI;

  for (int j = t; j < NB; j += PTHREADS) hist[j] = 0;
  __syncthreads();

  int bj[EPT];
  uint32_t pkj[EPT];
#pragma unroll
  for (int j = 0; j < EPT; ++j) {
    int i = j * PTHREADS + t;
    bj[j] = -1;
    if (i < cnt) {
      long e = e0 + i;
      int dstG, src;
      if (e < E) {
        dstG = NP + __builtin_nontemporal_load(&pt_dst[e]);
        src = __builtin_nontemporal_load(&pt_src[e]);
      } else {
        dstG = __builtin_nontemporal_load(&tp_dst[e - E]);
        src = NP + __builtin_nontemporal_load(&tp_src[e - E]);
      }
      int b = dstG >> BNSHIFT;
      bj[j] = b;
      pkj[j] = ((uint32_t)(dstG & (BN - 1)) << 20) | (uint32_t)src;
      atomicAdd(&hist[b], 1);
    }
  }
  __syncthreads();

  // inclusive scan of hist[0..NB) across PTHREADS slots (NB <= PTHREADS)
  int h = (t < NB) ? hist[t] : 0;
  int acc = h;
  sc[t] = h;
  __syncthreads();
  for (int off = 1; off < PTHREADS; off <<= 1) {
    int u = (t >= off) ? sc[t - off] : 0;
    __syncthreads();
    acc += u;
    sc[t] = acc;
    __syncthreads();
  }
  if (t < NB) {
    int ls = acc - h;  // exclusive prefix
    lstart[t] = ls;
    cur[t] = ls;
    gbase[t] = (h > 0) ? atomicAdd(&gCursor[t], h) : 0;
  }
  __syncthreads();

  // scatter into LDS, sorted by bucket; attach final global position
#pragma unroll
  for (int j = 0; j < EPT; ++j) {
    int b = bj[j];
    if (b >= 0) {
      int pos = atomicAdd(&cur[b], 1);
      int gpos = gbase[b] + (pos - lstart[b]);
      buf[pos] = ((uint64_t)(uint32_t)gpos << 32) | (uint64_t)pkj[j];
    }
  }
  __syncthreads();

  // coalesced drain: consecutive lanes hit consecutive slots within runs
  for (int i = t; i < cnt; i += PTHREADS) {
    uint64_t e = buf[i];
    pk[(uint32_t)(e >> 32)] = (uint32_t)e;
  }
}

// ---------------- per-bucket counting sort -> node-grouped CSR --------------
// Key = (dl, src>>SSH): per-node cols grouped by ascending source slice
// (round-9 pull win). 1024 threads: 1 node/thread, 16 slice bins each.
__global__ __launch_bounds__(1024) void local_csr_kernel(
    const int* __restrict__ bucketStart, const int* __restrict__ bucketCount,
    const uint32_t* __restrict__ pk, int* __restrict__ rowptr,
    int* __restrict__ col, int N, int TEtotal) {
  __shared__ int hist[BINS];   // 64 KB: counts -> exclusive prefixes -> cursors
  __shared__ int ssum[1024];
  int t = threadIdx.x;
  int b = blockIdx.x;
  for (int j = t; j < BINS; j += 1024) hist[j] = 0;
  __syncthreads();
  int beg = bucketStart[b], num = bucketCount[b];
  for (int i = t; i < num; i += 1024) {
    uint32_t w = pk[beg + i];
    int bin = (int)(((w >> 20) << 4) | ((w & 0xFFFFFu) >> SSH));
    atomicAdd(&hist[bin], 1);
  }
  __syncthreads();
  // scan 16384 bins: 16 serial per thread (one node) + 1024-wide block scan
  int b0 = t * 16;
  int local = 0;
#pragma unroll
  for (int j = 0; j < 16; ++j) local += hist[b0 + j];
  int acc = local;
  ssum[t] = local;
  __syncthreads();
  for (int off = 1; off < 1024; off <<= 1) {
    int u = (t >= off) ? ssum[t - off] : 0;
    __syncthreads();
    acc += u;
    ssum[t] = acc;
    __syncthreads();
  }
  int run = acc - local;  // exclusive prefix of this thread's node
  int node0 = (b << BNSHIFT) + t;
  if (node0 < N) rowptr[node0] = beg + run;
#pragma unroll
  for (int j = 0; j < 16; ++j) {
    int h = hist[b0 + j];
    hist[b0 + j] = run;
    run += h;
  }
  __syncthreads();
  for (int i = t; i < num; i += 1024) {
    uint32_t w = pk[beg + i];
    int bin = (int)(((w >> 20) << 4) | ((w & 0xFFFFFu) >> SSH));
    int pos = atomicAdd(&hist[bin], 1);
    col[beg + pos] = (int)(w & 0xFFFFFu);
  }
  if (b == 0 && t == 0) rowptr[N] = TEtotal;
}

// ---------------- pull aggregation: agg[n] = bf16(mean of src rows) ---------
// 8 lanes per node (8 nodes/wave), lane handles 8 dims via one uint4 (16 B).
// Natural node order; cols per node are source-slice-sorted (L2 sweep).
__global__ __launch_bounds__(256) void pull_kernel(
    const int* __restrict__ rowptr, const int* __restrict__ col,
    const uint16_t* __restrict__ base, uint16_t* __restrict__ agg, int N) {
  int node = blockIdx.x * 32 + (threadIdx.x >> 3);
  int c = threadIdx.x & 7;  // dims 8c..8c+7
  if (node >= N) return;
  int beg = rowptr[node], end = rowptr[node + 1];
  float s[8] = {0, 0, 0, 0, 0, 0, 0, 0};
  const uint16_t* bp = base + c * 8;
  int i = beg;
  for (; i + 4 <= end; i += 4) {
    int c0 = col[i], c1 = col[i + 1], c2 = col[i + 2], c3 = col[i + 3];
    uint4 v0 = *(const uint4*)(bp + (size_t)c0 * 64);
    uint4 v1 = *(const uint4*)(bp + (size_t)c1 * 64);
    uint4 v2 = *(const uint4*)(bp + (size_t)c2 * 64);
    uint4 v3 = *(const uint4*)(bp + (size_t)c3 * 64);
    acc8(s, v0); acc8(s, v1); acc8(s, v2); acc8(s, v3);
  }
  for (; i < end; ++i)
    acc8(s, *(const uint4*)(bp + (size_t)col[i] * 64));
  int deg = end - beg;
  float inv = 1.0f / (float)(deg > 1 ? deg : 1);
  union { uint16_t h[8]; uint4 v; } o;
#pragma unroll
  for (int j = 0; j < 8; ++j) o.h[j] = f2b(s[j] * inv);
  *(uint4*)(agg + (size_t)node * 64 + c * 8) = o.v;
}

// ---------------- fused transform: xout = relu(x@Wroot + agg@Wrel + b) ------
// FUSE=true (layer 1): writes S = emb + x + relu(...) instead of x2, killing
// the separate sum pass.
template <bool FUSE>
__global__ __launch_bounds__(256) void transform_kernel(
    const uint16_t* __restrict__ xpl, const uint16_t* __restrict__ xtr,
    const uint16_t* __restrict__ agg,
    const float* __restrict__ Wroot,
    const float* __restrict__ WrelP, const float* __restrict__ WrelT,
    const float* __restrict__ biasrow,
    const float* __restrict__ embP, const float* __restrict__ embT,
    uint16_t* __restrict__ xout, int NP, int NT, int BP) {
  int wave = threadIdx.x >> 6;
  int lane = threadIdx.x & 63;
  int m = lane & 15, q = lane >> 4;

  int wl, nw, ntiles, nodeBase;
  const uint16_t* xbase;
  const float* Wrel;
  const float* embBase;
  if ((int)blockIdx.x < BP) {
    wl = blockIdx.x * 4 + wave; nw = BP * 4; ntiles = NP / 16;
    xbase = xpl; Wrel = WrelP; nodeBase = 0; embBase = embP;
  } else {
    wl = (blockIdx.x - BP) * 4 + wave; nw = (gridDim.x - BP) * 4; ntiles = NT / 16;
    xbase = xtr; Wrel = WrelT; nodeBase = NP; embBase = embT;
  }

  // B fragments: B[k][n], lane n=16*ct+m, elems k=32*kc+8*q+i
  bf16x8 br[2][4], bl[2][4];
  for (int kc = 0; kc < 2; ++kc)
    for (int ct = 0; ct < 4; ++ct) {
      int n = 16 * ct + m;
      int k0 = 32 * kc + 8 * q;
      bf16x8 t0, t1;
      for (int i = 0; i < 8; ++i) {
        t0[i] = (short)f2b(Wroot[(size_t)(k0 + i) * 64 + n]);
        t1[i] = (short)f2b(Wrel[(size_t)(k0 + i) * 64 + n]);
      }
      br[kc][ct] = t0;
      bl[kc][ct] = t1;
    }
  float bv[4];
  for (int ct = 0; ct < 4; ++ct) bv[ct] = biasrow[16 * ct + m];

  for (int t = wl; t < ntiles; t += nw) {
    int rowLocal = t * 16 + m;  // A row: m = lane&15
    int nodeG = nodeBase + rowLocal;
    const uint16_t* xrow = xbase + (size_t)rowLocal * 64;
    bf16x8 ax0 = *(const bf16x8*)(xrow + 8 * q);
    bf16x8 ax1 = *(const bf16x8*)(xrow + 32 + 8 * q);

    const uint16_t* arow = agg + (size_t)nodeG * 64;
    bf16x8 aa0 = *(const bf16x8*)(arow + 8 * q);
    bf16x8 aa1 = *(const bf16x8*)(arow + 32 + 8 * q);

    f32x4 acc[4];
#pragma unroll
    for (int ct = 0; ct < 4; ++ct) acc[ct] = (f32x4){bv[ct], bv[ct], bv[ct], bv[ct]};
#pragma unroll
    for (int ct = 0; ct < 4; ++ct) {
      acc[ct] = __builtin_amdgcn_mfma_f32_16x16x32_bf16(ax0, br[0][ct], acc[ct], 0, 0, 0);
      acc[ct] = __builtin_amdgcn_mfma_f32_16x16x32_bf16(ax1, br[1][ct], acc[ct], 0, 0, 0);
      acc[ct] = __builtin_amdgcn_mfma_f32_16x16x32_bf16(aa0, bl[0][ct], acc[ct], 0, 0, 0);
      acc[ct] = __builtin_amdgcn_mfma_f32_16x16x32_bf16(aa1, bl[1][ct], acc[ct], 0, 0, 0);
    }
    // D: row = 4*q + r, col = 16*ct + m
    int nodeRow0 = nodeBase + t * 16;
    int localRow0 = t * 16;
#pragma unroll
    for (int ct = 0; ct < 4; ++ct)
#pragma unroll
      for (int r = 0; r < 4; ++r) {
        float v = acc[ct][r];
        v = v > 0.0f ? v : 0.0f;
        int colIdx = 16 * ct + m;
        size_t go = (size_t)(nodeRow0 + 4 * q + r) * 64 + colIdx;
        if (FUSE) {
          size_t lo = (size_t)(localRow0 + 4 * q + r) * 64 + colIdx;
          float e = embBase[lo];
          float x1f = b2f_lo((uint32_t)xbase[lo]);
          xout[go] = f2b(e + x1f + v);
        } else {
          xout[go] = f2b(v);
        }
      }
  }
}

// ---------------- link scores: (1/9) * dot(S_p, S_t) ------------------------
// 8 lanes per pair, 8 dims each via uint4 (16 B).
__global__ void score_kernel(const int* __restrict__ ell_pl,
                             const int* __restrict__ ell_tr,
                             const uint16_t* __restrict__ S,
                             float* __restrict__ out, int EP, int NP) {
  long g = (long)blockIdx.x * blockDim.x + threadIdx.x;
  long pair = g >> 3;
  int c = (int)(g & 7);
  if (pair >= EP) return;
  int p = __builtin_nontemporal_load(&ell_pl[pair]);
  int t = __builtin_nontemporal_load(&ell_tr[pair]);
  uint4 vp = *(const uint4*)(S + (size_t)p * 64 + c * 8);
  uint4 vt = *(const uint4*)(S + (size_t)(NP + t) * 64 + c * 8);
  float partial = b2f_lo(vp.x) * b2f_lo(vt.x) + b2f_hi(vp.x) * b2f_hi(vt.x)
                + b2f_lo(vp.y) * b2f_lo(vt.y) + b2f_hi(vp.y) * b2f_hi(vt.y)
                + b2f_lo(vp.z) * b2f_lo(vt.z) + b2f_hi(vp.z) * b2f_hi(vt.z)
                + b2f_lo(vp.w) * b2f_lo(vt.w) + b2f_hi(vp.w) * b2f_hi(vt.w);
  partial += __shfl_xor(partial, 1);
  partial += __shfl_xor(partial, 2);
  partial += __shfl_xor(partial, 4);
  if (c == 0) __builtin_nontemporal_store(partial * (1.0f / 9.0f), &out[pair]);
}

extern "C" void kernel_launch(void* const* d_in, const int* in_sizes, int n_in,
                              void* d_out, int out_size, void* d_ws, size_t ws_size,
                              hipStream_t stream) {
  const float* emb_pl = (const float*)d_in[0];
  const float* emb_tr = (const float*)d_in[1];
  const float* W_rel = (const float*)d_in[2];   // [L,2,64,64] f32
  const float* W_root = (const float*)d_in[3];  // [L,64,64] f32
  const float* bias = (const float*)d_in[4];    // [L,64] f32
  const int* pt_src = (const int*)d_in[7];
  const int* pt_dst = (const int*)d_in[8];
  const int* tp_src = (const int*)d_in[9];
  const int* tp_dst = (const int*)d_in[10];
  const int* ell_pl = (const int*)d_in[11];
  const int* ell_tr = (const int*)d_in[12];
  float* out = (float*)d_out;

  const int NP = in_sizes[5];
  const int NT = in_sizes[6];
  const int E = in_sizes[7];
  const int EP = in_sizes[11];
  const int N = NP + NT;
  const long TE = 2L * E;
  const int NB = (N + BN - 1) / BN;

  char* ws = (char*)d_ws;
  size_t off = 0;
  uint16_t* agg = (uint16_t*)(ws + off); off += (size_t)N * 64 * 2;   // bf16
  uint16_t* x1  = (uint16_t*)(ws + off); off += (size_t)N * 64 * 2;   // bf16
  uint16_t* xb0 = (uint16_t*)(ws + off); off += (size_t)N * 64 * 2;   // bf16 emb copy
  uint16_t* S   = (uint16_t*)(ws + off); off += (size_t)N * 64 * 2;   // node sums
  uint32_t* pk  = (uint32_t*)(ws + off); off += (size_t)TE * 4;
  int* col      = (int*)(ws + off);      off += (size_t)TE * 4;
  int* rowptr   = (int*)(ws + off);      off += (size_t)(N + 1) * 4;
  int* bucketCount = (int*)(ws + off);   off += (size_t)NB * 4;
  int* bucketStart = (int*)(ws + off);   off += (size_t)NB * 4;
  int* gCursor     = (int*)(ws + off);   off += (size_t)NB * 4;

  const int TB = 256;
  long cvt = ((long)N * 64 / 8 + TB - 1) / TB;
  int pullBlocks = (N + 31) / 32;
  int scoreBlocks = (int)(((long)EP * 8 + TB - 1) / TB);
  int partBlocks = (int)((TE + PTI - 1) / PTI);
  const int BP = 256, GT = 1024;  // transform grid split

  // ---- bf16 embedding copy (used by pull0 + transform0) ----
  convert_kernel<<<(int)cvt, TB, 0, stream>>>(emb_pl, emb_tr, xb0, NP, N);

  // ---- bucket build (once; reused by both layers) ----
  hipMemsetAsync(bucketCount, 0, (size_t)NB * 4, stream);
  bucket_hist_kernel<<<128, TB, NB * 4, stream>>>(pt_dst, tp_dst, bucketCount,
                                                  E, NP, NB);
  bucket_scan_kernel<<<1, 1024, 0, stream>>>(bucketCount, bucketStart, gCursor, NB);
  partition_kernel<<<partBlocks, PTHREADS, 0, stream>>>(
      pt_src, pt_dst, tp_src, tp_dst, gCursor, pk, E, NP, NB);
  local_csr_kernel<<<NB, 1024, 0, stream>>>(bucketStart, bucketCount, pk,
                                            rowptr, col, N, (int)TE);

  // ---- layer 0 (x = bf16 embedding copy) ----
  pull_kernel<<<pullBlocks, TB, 0, stream>>>(rowptr, col, xb0, agg, N);
  transform_kernel<false><<<GT, TB, 0, stream>>>(
      xb0, xb0 + (size_t)NP * 64, agg, W_root + 0 * 4096, W_rel + 1 * 4096,
      W_rel + 0 * 4096, bias + 0, nullptr, nullptr, x1, NP, NT, BP);

  // ---- layer 1 (x = x1); epilogue fuses S = emb + x1 + relu(h2) ----
  pull_kernel<<<pullBlocks, TB, 0, stream>>>(rowptr, col, x1, agg, N);
  transform_kernel<true><<<GT, TB, 0, stream>>>(
      x1, x1 + (size_t)NP * 64, agg, W_root + 1 * 4096, W_rel + 3 * 4096,
      W_rel + 2 * 4096, bias + 64, emb_pl, emb_tr, S, NP, NT, BP);

  // ---- link scores ----
  score_kernel<<<scoreBlocks, TB, 0, stream>>>(ell_pl, ell_tr, S, out, EP, NP);
}

// Round 11
// 527.217 us; speedup vs baseline: 1.0316x; 1.0175x over previous
//
#include <hip/hip_runtime.h>
#include <stdint.h>

typedef __attribute__((ext_vector_type(8))) short bf16x8;
typedef __attribute__((ext_vector_type(4))) float f32x4;

#define BN 1024      // dst nodes per bucket (power of 2)
#define BNSHIFT 10
#define MAXNB 512    // supports N up to 512*1024
#define PTI 8192     // edges per partition tile
#define PTHREADS 1024
#define EPT (PTI / PTHREADS)   // 8
#define SL 16        // source slices per node (sorted ascending -> L2 sweep)
#define SSH 15       // slice = src >> SSH
#define BINS (BN * SL)

static __device__ __forceinline__ float b2f_lo(uint32_t w) {
  union { uint32_t u; float f; } c; c.u = w << 16; return c.f;
}
static __device__ __forceinline__ float b2f_hi(uint32_t w) {
  union { uint32_t u; float f; } c; c.u = w & 0xffff0000u; return c.f;
}
static __device__ __forceinline__ uint16_t f2b(float f) {
  union { float f; uint32_t u; } c; c.f = f;
  return (uint16_t)((c.u + 0x7fffu + ((c.u >> 16) & 1u)) >> 16);
}
static __device__ __forceinline__ void acc8(float* s, uint4 v) {
  s[0] += b2f_lo(v.x); s[1] += b2f_hi(v.x);
  s[2] += b2f_lo(v.y); s[3] += b2f_hi(v.y);
  s[4] += b2f_lo(v.z); s[5] += b2f_hi(v.z);
  s[6] += b2f_lo(v.w); s[7] += b2f_hi(v.w);
}

// -------- fused: fp32->bf16 embedding convert  +  bucket histogram ----------
// blockIdx < cvtBlocks: convert lane work; else: grid-stride dst histogram.
// One dispatch instead of two (saves a launch + drain cycle).
__global__ __launch_bounds__(256) void convert_hist_kernel(
    const float* __restrict__ emb_pl, const float* __restrict__ emb_tr,
    uint16_t* __restrict__ xb,
    const int* __restrict__ pt_dst, const int* __restrict__ tp_dst,
    int* __restrict__ bucketCount,
    int NP, int N, int E, int NB, int cvtBlocks) {
  __shared__ int hist[MAXNB];
  int t = threadIdx.x;
  if ((int)blockIdx.x < cvtBlocks) {
    long g = (long)blockIdx.x * 256 + t;
    long base8 = g * 8;
    long total = (long)N * 64;
    if (base8 >= total) return;
    long plEnd = (long)NP * 64;  // divisible by 8, no straddle
    const float* src = (base8 < plEnd) ? (emb_pl + base8) : (emb_tr + (base8 - plEnd));
    f32x4 a = *(const f32x4*)src;
    f32x4 b = *(const f32x4*)(src + 4);
    union { uint16_t h[8]; uint4 v; } o;
    o.h[0] = f2b(a.x); o.h[1] = f2b(a.y); o.h[2] = f2b(a.z); o.h[3] = f2b(a.w);
    o.h[4] = f2b(b.x); o.h[5] = f2b(b.y); o.h[6] = f2b(b.z); o.h[7] = f2b(b.w);
    *(uint4*)(xb + base8) = o.v;
  } else {
    int hb = blockIdx.x - cvtBlocks;  // 0..127
    for (int b = t; b < NB; b += 256) hist[b] = 0;
    __syncthreads();
    long total = 2L * E;
    long stride = 128L * 256;
    for (long e = (long)hb * 256 + t; e < total; e += stride) {
      int dstG = (e < E) ? (NP + pt_dst[e]) : tp_dst[e - E];
      atomicAdd(&hist[dstG >> BNSHIFT], 1);
    }
    __syncthreads();
    for (int b = t; b < NB; b += 256) {
      int h = hist[b];
      if (h > 0) atomicAdd(&bucketCount[b], h);
    }
  }
}

// ---------------- exclusive scan of counts (1 block, generic NB) ------------
__global__ __launch_bounds__(1024) void bucket_scan_kernel(
    const int* __restrict__ bucketCount, int* __restrict__ bucketStart,
    int* __restrict__ gCursor, int NB) {
  __shared__ int s[1024];
  int t = threadIdx.x;
  int K = (NB + 1023) >> 10;
  int b0 = t * K;
  int local = 0;
  for (int j = 0; j < K; ++j) {
    int b = b0 + j;
    if (b < NB) local += bucketCount[b];
  }
  int acc = local;
  s[t] = local;
  __syncthreads();
  for (int off = 1; off < 1024; off <<= 1) {
    int u = (t >= off) ? s[t - off] : 0;
    __syncthreads();
    acc += u;
    s[t] = acc;
    __syncthreads();
  }
  int run = acc - local;  // exclusive prefix of this thread's chunk
  for (int j = 0; j < K; ++j) {
    int b = b0 + j;
    if (b < NB) {
      bucketStart[b] = run;
      gCursor[b] = run;
      run += bucketCount[b];
    }
  }
}

// ---------------- partition: LDS tile-sort, then coalesced write ------------
__global__ __launch_bounds__(PTHREADS) void partition_kernel(
    const int* __restrict__ pt_src, const int* __restrict__ pt_dst,
    const int* __restrict__ tp_src, const int* __restrict__ tp_dst,
    int* __restrict__ gCursor, uint32_t* __restrict__ pk,
    int E, int NP, int NB) {
  __shared__ uint64_t buf[PTI];    // 64 KB sorted staging
  __shared__ int hist[MAXNB];
  __shared__ int lstart[MAXNB];
  __shared__ int gbase[MAXNB];
  __shared__ int cur[MAXNB];
  __shared__ int sc[PTHREADS];
  int t = threadIdx.x;
  long total = 2L * E;
  long e0 = (long)blockIdx.x * PTI;
  long rem = total - e0;
  int cnt = (rem < (long)PTI) ? (int)rem : PTI;

  for (int j = t; j < NB; j += PTHREADS) hist[j] = 0;
  __syncthreads();

  int bj[EPT];
  uint32_t pkj[EPT];
#pragma unroll
  for (int j = 0; j < EPT; ++j) {
    int i = j * PTHREADS + t;
    bj[j] = -1;
    if (i < cnt) {
      long e = e0 + i;
      int dstG, src;
      if (e < E) {
        dstG = NP + __builtin_nontemporal_load(&pt_dst[e]);
        src = __builtin_nontemporal_load(&pt_src[e]);
      } else {
        dstG = __builtin_nontemporal_load(&tp_dst[e - E]);
        src = NP + __builtin_nontemporal_load(&tp_src[e - E]);
      }
      int b = dstG >> BNSHIFT;
      bj[j] = b;
      pkj[j] = ((uint32_t)(dstG & (BN - 1)) << 20) | (uint32_t)src;
      atomicAdd(&hist[b], 1);
    }
  }
  __syncthreads();

  // inclusive scan of hist[0..NB) across PTHREADS slots (NB <= PTHREADS)
  int h = (t < NB) ? hist[t] : 0;
  int acc = h;
  sc[t] = h;
  __syncthreads();
  for (int off = 1; off < PTHREADS; off <<= 1) {
    int u = (t >= off) ? sc[t - off] : 0;
    __syncthreads();
    acc += u;
    sc[t] = acc;
    __syncthreads();
  }
  if (t < NB) {
    int ls = acc - h;  // exclusive prefix
    lstart[t] = ls;
    cur[t] = ls;
    gbase[t] = (h > 0) ? atomicAdd(&gCursor[t], h) : 0;
  }
  __syncthreads();

  // scatter into LDS, sorted by bucket; attach final global position
#pragma unroll
  for (int j = 0; j < EPT; ++j) {
    int b = bj[j];
    if (b >= 0) {
      int pos = atomicAdd(&cur[b], 1);
      int gpos = gbase[b] + (pos - lstart[b]);
      buf[pos] = ((uint64_t)(uint32_t)gpos << 32) | (uint64_t)pkj[j];
    }
  }
  __syncthreads();

  // coalesced drain: consecutive lanes hit consecutive slots within runs
  for (int i = t; i < cnt; i += PTHREADS) {
    uint64_t e = buf[i];
    pk[(uint32_t)(e >> 32)] = (uint32_t)e;
  }
}

// ---------------- per-bucket counting sort -> node-grouped CSR --------------
// Key = (dl, src>>SSH): per-node cols grouped by ascending source slice.
__global__ __launch_bounds__(1024) void local_csr_kernel(
    const int* __restrict__ bucketStart, const int* __restrict__ bucketCount,
    const uint32_t* __restrict__ pk, int* __restrict__ rowptr,
    int* __restrict__ col, int N, int TEtotal) {
  __shared__ int hist[BINS];   // 64 KB: counts -> exclusive prefixes -> cursors
  __shared__ int ssum[1024];
  int t = threadIdx.x;
  int b = blockIdx.x;
  for (int j = t; j < BINS; j += 1024) hist[j] = 0;
  __syncthreads();
  int beg = bucketStart[b], num = bucketCount[b];
  for (int i = t; i < num; i += 1024) {
    uint32_t w = pk[beg + i];
    int bin = (int)(((w >> 20) << 4) | ((w & 0xFFFFFu) >> SSH));
    atomicAdd(&hist[bin], 1);
  }
  __syncthreads();
  // scan 16384 bins: 16 serial per thread (one node) + 1024-wide block scan
  int b0 = t * 16;
  int local = 0;
#pragma unroll
  for (int j = 0; j < 16; ++j) local += hist[b0 + j];
  int acc = local;
  ssum[t] = local;
  __syncthreads();
  for (int off = 1; off < 1024; off <<= 1) {
    int u = (t >= off) ? ssum[t - off] : 0;
    __syncthreads();
    acc += u;
    ssum[t] = acc;
    __syncthreads();
  }
  int run = acc - local;  // exclusive prefix of this thread's node
  int node0 = (b << BNSHIFT) + t;
  if (node0 < N) rowptr[node0] = beg + run;
#pragma unroll
  for (int j = 0; j < 16; ++j) {
    int h = hist[b0 + j];
    hist[b0 + j] = run;
    run += h;
  }
  __syncthreads();
  for (int i = t; i < num; i += 1024) {
    uint32_t w = pk[beg + i];
    int bin = (int)(((w >> 20) << 4) | ((w & 0xFFFFFu) >> SSH));
    int pos = atomicAdd(&hist[bin], 1);
    col[beg + pos] = (int)(w & 0xFFFFFu);
  }
  if (b == 0 && t == 0) rowptr[N] = TEtotal;
}

// ---------------- pull aggregation: agg[n] = bf16(mean of src rows) ---------
// 8 lanes per node (8 nodes/wave), lane handles 8 dims via one uint4 (16 B).
__global__ __launch_bounds__(256) void pull_kernel(
    const int* __restrict__ rowptr, const int* __restrict__ col,
    const uint16_t* __restrict__ base, uint16_t* __restrict__ agg, int N) {
  int node = blockIdx.x * 32 + (threadIdx.x >> 3);
  int c = threadIdx.x & 7;  // dims 8c..8c+7
  if (node >= N) return;
  int beg = rowptr[node], end = rowptr[node + 1];
  float s[8] = {0, 0, 0, 0, 0, 0, 0, 0};
  const uint16_t* bp = base + c * 8;
  int i = beg;
  for (; i + 4 <= end; i += 4) {
    int c0 = col[i], c1 = col[i + 1], c2 = col[i + 2], c3 = col[i + 3];
    uint4 v0 = *(const uint4*)(bp + (size_t)c0 * 64);
    uint4 v1 = *(const uint4*)(bp + (size_t)c1 * 64);
    uint4 v2 = *(const uint4*)(bp + (size_t)c2 * 64);
    uint4 v3 = *(const uint4*)(bp + (size_t)c3 * 64);
    acc8(s, v0); acc8(s, v1); acc8(s, v2); acc8(s, v3);
  }
  for (; i < end; ++i)
    acc8(s, *(const uint4*)(bp + (size_t)col[i] * 64));
  int deg = end - beg;
  float inv = 1.0f / (float)(deg > 1 ? deg : 1);
  union { uint16_t h[8]; uint4 v; } o;
#pragma unroll
  for (int j = 0; j < 8; ++j) o.h[j] = f2b(s[j] * inv);
  *(uint4*)(agg + (size_t)node * 64 + c * 8) = o.v;
}

// ---------------- fused transform: xout = relu(x@Wroot + agg@Wrel + b) ------
// Epilogue now stages the relu'd tile in WAVE-PRIVATE LDS (no barriers: each
// wave owns its tile[wave] slab; within-wave LDS RAW is ordered by lgkmcnt),
// then reads back row-major with (g,c) roles -> all epilogue global accesses
// are full-width vectors (f32x4 emb, uint4 x1, uint4 store) instead of 48
// scalar ops per tile. Row stride padded 64->68 floats (bank-conflict-free).
// Bit-exact vs the scalar epilogue (same f32 values through f2b).
// FUSE=true (layer 1): writes S = emb + x + relu(...) (sum pass fused).
template <bool FUSE>
__global__ __launch_bounds__(256) void transform_kernel(
    const uint16_t* __restrict__ xpl, const uint16_t* __restrict__ xtr,
    const uint16_t* __restrict__ agg,
    const float* __restrict__ Wroot,
    const float* __restrict__ WrelP, const float* __restrict__ WrelT,
    const float* __restrict__ biasrow,
    const float* __restrict__ embP, const float* __restrict__ embT,
    uint16_t* __restrict__ xout, int NP, int NT, int BP) {
  __shared__ float tile[4][16][68];   // wave-private 16x64 (+4 pad) staging
  int wave = threadIdx.x >> 6;
  int lane = threadIdx.x & 63;
  int m = lane & 15, q = lane >> 4;   // MFMA roles
  int g = lane >> 3, c = lane & 7;    // epilogue row roles
  float (*tp)[68] = tile[wave];

  int wl, nw, ntiles, nodeBase;
  const uint16_t* xbase;
  const float* Wrel;
  const float* embBase;
  if ((int)blockIdx.x < BP) {
    wl = blockIdx.x * 4 + wave; nw = BP * 4; ntiles = NP / 16;
    xbase = xpl; Wrel = WrelP; nodeBase = 0; embBase = embP;
  } else {
    wl = (blockIdx.x - BP) * 4 + wave; nw = (gridDim.x - BP) * 4; ntiles = NT / 16;
    xbase = xtr; Wrel = WrelT; nodeBase = NP; embBase = embT;
  }

  // B fragments: B[k][n], lane n=16*ct+m, elems k=32*kc+8*q+i
  bf16x8 br[2][4], bl[2][4];
  for (int kc = 0; kc < 2; ++kc)
    for (int ct = 0; ct < 4; ++ct) {
      int n = 16 * ct + m;
      int k0 = 32 * kc + 8 * q;
      bf16x8 t0, t1;
      for (int i = 0; i < 8; ++i) {
        t0[i] = (short)f2b(Wroot[(size_t)(k0 + i) * 64 + n]);
        t1[i] = (short)f2b(Wrel[(size_t)(k0 + i) * 64 + n]);
      }
      br[kc][ct] = t0;
      bl[kc][ct] = t1;
    }
  float bv[4];
  for (int ct = 0; ct < 4; ++ct) bv[ct] = biasrow[16 * ct + m];

  for (int t = wl; t < ntiles; t += nw) {
    int rowLocal = t * 16 + m;  // A row: m = lane&15
    int nodeG = nodeBase + rowLocal;
    const uint16_t* xrow = xbase + (size_t)rowLocal * 64;
    bf16x8 ax0 = *(const bf16x8*)(xrow + 8 * q);
    bf16x8 ax1 = *(const bf16x8*)(xrow + 32 + 8 * q);

    const uint16_t* arow = agg + (size_t)nodeG * 64;
    bf16x8 aa0 = *(const bf16x8*)(arow + 8 * q);
    bf16x8 aa1 = *(const bf16x8*)(arow + 32 + 8 * q);

    f32x4 acc[4];
#pragma unroll
    for (int ct = 0; ct < 4; ++ct) acc[ct] = (f32x4){bv[ct], bv[ct], bv[ct], bv[ct]};
#pragma unroll
    for (int ct = 0; ct < 4; ++ct) {
      acc[ct] = __builtin_amdgcn_mfma_f32_16x16x32_bf16(ax0, br[0][ct], acc[ct], 0, 0, 0);
      acc[ct] = __builtin_amdgcn_mfma_f32_16x16x32_bf16(ax1, br[1][ct], acc[ct], 0, 0, 0);
      acc[ct] = __builtin_amdgcn_mfma_f32_16x16x32_bf16(aa0, bl[0][ct], acc[ct], 0, 0, 0);
      acc[ct] = __builtin_amdgcn_mfma_f32_16x16x32_bf16(aa1, bl[1][ct], acc[ct], 0, 0, 0);
    }
    // stage relu'd D tile: row = 4*q + r, col = 16*ct + m
#pragma unroll
    for (int ct = 0; ct < 4; ++ct)
#pragma unroll
      for (int r = 0; r < 4; ++r) {
        float v = acc[ct][r];
        tp[4 * q + r][16 * ct + m] = v > 0.0f ? v : 0.0f;
      }
    // vector epilogue: lane handles rows {g, g+8}, dims [8c, 8c+8)
    int localRow0 = t * 16;
    int nodeRow0 = nodeBase + localRow0;
#pragma unroll
    for (int rr = 0; rr < 2; ++rr) {
      int row = g + rr * 8;
      f32x4 va = *(const f32x4*)&tp[row][8 * c];
      f32x4 vb = *(const f32x4*)&tp[row][8 * c + 4];
      union { uint16_t h[8]; uint4 v; } o;
      if (FUSE) {
        const float* erow = embBase + (size_t)(localRow0 + row) * 64 + 8 * c;
        f32x4 ea = *(const f32x4*)erow;
        f32x4 eb = *(const f32x4*)(erow + 4);
        uint4 xv = *(const uint4*)(xbase + (size_t)(localRow0 + row) * 64 + 8 * c);
        o.h[0] = f2b(ea.x + b2f_lo(xv.x) + va.x);
        o.h[1] = f2b(ea.y + b2f_hi(xv.x) + va.y);
        o.h[2] = f2b(ea.z + b2f_lo(xv.y) + va.z);
        o.h[3] = f2b(ea.w + b2f_hi(xv.y) + va.w);
        o.h[4] = f2b(eb.x + b2f_lo(xv.z) + vb.x);
        o.h[5] = f2b(eb.y + b2f_hi(xv.z) + vb.y);
        o.h[6] = f2b(eb.z + b2f_lo(xv.w) + vb.z);
        o.h[7] = f2b(eb.w + b2f_hi(xv.w) + vb.w);
      } else {
        o.h[0] = f2b(va.x); o.h[1] = f2b(va.y);
        o.h[2] = f2b(va.z); o.h[3] = f2b(va.w);
        o.h[4] = f2b(vb.x); o.h[5] = f2b(vb.y);
        o.h[6] = f2b(vb.z); o.h[7] = f2b(vb.w);
      }
      *(uint4*)(xout + (size_t)(nodeRow0 + row) * 64 + 8 * c) = o.v;
    }
  }
}

// ---------------- link scores: (1/9) * dot(S_p, S_t) ------------------------
// 8 lanes per pair, 8 dims each via uint4 (16 B).
__global__ void score_kernel(const int* __restrict__ ell_pl,
                             const int* __restrict__ ell_tr,
                             const uint16_t* __restrict__ S,
                             float* __restrict__ out, int EP, int NP) {
  long g = (long)blockIdx.x * blockDim.x + threadIdx.x;
  long pair = g >> 3;
  int c = (int)(g & 7);
  if (pair >= EP) return;
  int p = __builtin_nontemporal_load(&ell_pl[pair]);
  int t = __builtin_nontemporal_load(&ell_tr[pair]);
  uint4 vp = *(const uint4*)(S + (size_t)p * 64 + c * 8);
  uint4 vt = *(const uint4*)(S + (size_t)(NP + t) * 64 + c * 8);
  float partial = b2f_lo(vp.x) * b2f_lo(vt.x) + b2f_hi(vp.x) * b2f_hi(vt.x)
                + b2f_lo(vp.y) * b2f_lo(vt.y) + b2f_hi(vp.y) * b2f_hi(vt.y)
                + b2f_lo(vp.z) * b2f_lo(vt.z) + b2f_hi(vp.z) * b2f_hi(vt.z)
                + b2f_lo(vp.w) * b2f_lo(vt.w) + b2f_hi(vp.w) * b2f_hi(vt.w);
  partial += __shfl_xor(partial, 1);
  partial += __shfl_xor(partial, 2);
  partial += __shfl_xor(partial, 4);
  if (c == 0) __builtin_nontemporal_store(partial * (1.0f / 9.0f), &out[pair]);
}

extern "C" void kernel_launch(void* const* d_in, const int* in_sizes, int n_in,
                              void* d_out, int out_size, void* d_ws, size_t ws_size,
                              hipStream_t stream) {
  const float* emb_pl = (const float*)d_in[0];
  const float* emb_tr = (const float*)d_in[1];
  const float* W_rel = (const float*)d_in[2];   // [L,2,64,64] f32
  const float* W_root = (const float*)d_in[3];  // [L,64,64] f32
  const float* bias = (const float*)d_in[4];    // [L,64] f32
  const int* pt_src = (const int*)d_in[7];
  const int* pt_dst = (const int*)d_in[8];
  const int* tp_src = (const int*)d_in[9];
  const int* tp_dst = (const int*)d_in[10];
  const int* ell_pl = (const int*)d_in[11];
  const int* ell_tr = (const int*)d_in[12];
  float* out = (float*)d_out;

  const int NP = in_sizes[5];
  const int NT = in_sizes[6];
  const int E = in_sizes[7];
  const int EP = in_sizes[11];
  const int N = NP + NT;
  const long TE = 2L * E;
  const int NB = (N + BN - 1) / BN;

  char* ws = (char*)d_ws;
  size_t off = 0;
  uint16_t* agg = (uint16_t*)(ws + off); off += (size_t)N * 64 * 2;   // bf16
  uint16_t* x1  = (uint16_t*)(ws + off); off += (size_t)N * 64 * 2;   // bf16
  uint16_t* xb0 = (uint16_t*)(ws + off); off += (size_t)N * 64 * 2;   // bf16 emb copy
  uint16_t* S   = (uint16_t*)(ws + off); off += (size_t)N * 64 * 2;   // node sums
  uint32_t* pk  = (uint32_t*)(ws + off); off += (size_t)TE * 4;
  int* col      = (int*)(ws + off);      off += (size_t)TE * 4;
  int* rowptr   = (int*)(ws + off);      off += (size_t)(N + 1) * 4;
  int* bucketCount = (int*)(ws + off);   off += (size_t)NB * 4;
  int* bucketStart = (int*)(ws + off);   off += (size_t)NB * 4;
  int* gCursor     = (int*)(ws + off);   off += (size_t)NB * 4;

  const int TB = 256;
  int cvtBlocks = (int)(((long)N * 64 / 8 + TB - 1) / TB);
  int pullBlocks = (N + 31) / 32;
  int scoreBlocks = (int)(((long)EP * 8 + TB - 1) / TB);
  int partBlocks = (int)((TE + PTI - 1) / PTI);
  const int BP = 256, GT = 1024;  // transform grid split

  // ---- bucket-count zero, then fused convert + histogram (one dispatch) ----
  hipMemsetAsync(bucketCount, 0, (size_t)NB * 4, stream);
  convert_hist_kernel<<<cvtBlocks + 128, TB, 0, stream>>>(
      emb_pl, emb_tr, xb0, pt_dst, tp_dst, bucketCount, NP, N, E, NB, cvtBlocks);

  // ---- bucket build (once; reused by both layers) ----
  bucket_scan_kernel<<<1, 1024, 0, stream>>>(bucketCount, bucketStart, gCursor, NB);
  partition_kernel<<<partBlocks, PTHREADS, 0, stream>>>(
      pt_src, pt_dst, tp_src, tp_dst, gCursor, pk, E, NP, NB);
  local_csr_kernel<<<NB, 1024, 0, stream>>>(bucketStart, bucketCount, pk,
                                            rowptr, col, N, (int)TE);

  // ---- layer 0 (x = bf16 embedding copy) ----
  pull_kernel<<<pullBlocks, TB, 0, stream>>>(rowptr, col, xb0, agg, N);
  transform_kernel<false><<<GT, TB, 0, stream>>>(
      xb0, xb0 + (size_t)NP * 64, agg, W_root + 0 * 4096, W_rel + 1 * 4096,
      W_rel + 0 * 4096, bias + 0, nullptr, nullptr, x1, NP, NT, BP);

  // ---- layer 1 (x = x1); epilogue fuses S = emb + x1 + relu(h2) ----
  pull_kernel<<<pullBlocks, TB, 0, stream>>>(rowptr, col, x1, agg, N);
  transform_kernel<true><<<GT, TB, 0, stream>>>(
      x1, x1 + (size_t)NP * 64, agg, W_root + 1 * 4096, W_rel + 3 * 4096,
      W_rel + 2 * 4096, bias + 64, emb_pl, emb_tr, S, NP, NT, BP);

  // ---- link scores ----
  score_kernel<<<scoreBlocks, TB, 0, stream>>>(ell_pl, ell_tr, S, out, EP, NP);
}

// Round 12
// 499.439 us; speedup vs baseline: 1.0890x; 1.0556x over previous
//
#include <hip/hip_runtime.h>
#include <stdint.h>

typedef __attribute__((ext_vector_type(8))) short bf16x8;
typedef __attribute__((ext_vector_type(4))) float f32x4;

#define BN 1024      // dst nodes per bucket (power of 2)
#define BNSHIFT 10
#define MAXNB 512    // supports N up to 512*1024
#define PTI 8192     // edges per partition tile
#define PTHREADS 1024
#define EPT (PTI / PTHREADS)   // 8
#define SL 16        // source slices per node (sorted ascending -> L2 sweep)
#define SSH 15       // slice = src >> SSH
#define BINS (BN * SL)

static __device__ __forceinline__ float b2f_lo(uint32_t w) {
  union { uint32_t u; float f; } c; c.u = w << 16; return c.f;
}
static __device__ __forceinline__ float b2f_hi(uint32_t w) {
  union { uint32_t u; float f; } c; c.u = w & 0xffff0000u; return c.f;
}
static __device__ __forceinline__ uint16_t f2b(float f) {
  union { float f; uint32_t u; } c; c.f = f;
  return (uint16_t)((c.u + 0x7fffu + ((c.u >> 16) & 1u)) >> 16);
}
static __device__ __forceinline__ void acc8(float* s, uint4 v) {
  s[0] += b2f_lo(v.x); s[1] += b2f_hi(v.x);
  s[2] += b2f_lo(v.y); s[3] += b2f_hi(v.y);
  s[4] += b2f_lo(v.z); s[5] += b2f_hi(v.z);
  s[6] += b2f_lo(v.w); s[7] += b2f_hi(v.w);
}

// ---------------- fp32 -> bf16 embedding conversion (into xb buffer) --------
__global__ __launch_bounds__(256) void convert_kernel(
    const float* __restrict__ emb_pl, const float* __restrict__ emb_tr,
    uint16_t* __restrict__ xb, int NP, int N) {
  long g = (long)blockIdx.x * 256 + threadIdx.x;
  long base8 = g * 8;
  long total = (long)N * 64;
  if (base8 >= total) return;
  long plEnd = (long)NP * 64;  // divisible by 8, no straddle
  const float* src = (base8 < plEnd) ? (emb_pl + base8) : (emb_tr + (base8 - plEnd));
  f32x4 a = *(const f32x4*)src;
  f32x4 b = *(const f32x4*)(src + 4);
  union { uint16_t h[8]; uint4 v; } o;
  o.h[0] = f2b(a.x); o.h[1] = f2b(a.y); o.h[2] = f2b(a.z); o.h[3] = f2b(a.w);
  o.h[4] = f2b(b.x); o.h[5] = f2b(b.y); o.h[6] = f2b(b.z); o.h[7] = f2b(b.w);
  *(uint4*)(xb + base8) = o.v;
}

// ---------------- bucket histogram over dst (both relations) ----------------
// 1024 blocks (4/CU), int4-vectorized edge reads: 4M edges -> ~4 LDS atomics
// per thread instead of 128 serial ones on a 128-block tail grid.
__global__ __launch_bounds__(256) void bucket_hist_kernel(
    const int* __restrict__ pt_dst, const int* __restrict__ tp_dst,
    int* __restrict__ bucketCount, int E, int NP, int NB) {
  extern __shared__ int hist[];
  int t = threadIdx.x;
  for (int b = t; b < NB; b += 256) hist[b] = 0;
  __syncthreads();
  long q = E >> 2;          // int4 chunks per relation
  long total4 = 2 * q;
  long stride = (long)gridDim.x * 256;
  for (long i = (long)blockIdx.x * 256 + t; i < total4; i += stride) {
    int4 v;
    int base;
    if (i < q) { v = ((const int4*)pt_dst)[i]; base = NP; }
    else       { v = ((const int4*)tp_dst)[i - q]; base = 0; }
    atomicAdd(&hist[(base + v.x) >> BNSHIFT], 1);
    atomicAdd(&hist[(base + v.y) >> BNSHIFT], 1);
    atomicAdd(&hist[(base + v.z) >> BNSHIFT], 1);
    atomicAdd(&hist[(base + v.w) >> BNSHIFT], 1);
  }
  // scalar tail (E % 4)
  if (blockIdx.x == 0) {
    for (int e = (int)(q << 2) + t; e < E; e += 256) {
      atomicAdd(&hist[(NP + pt_dst[e]) >> BNSHIFT], 1);
      atomicAdd(&hist[tp_dst[e] >> BNSHIFT], 1);
    }
  }
  __syncthreads();
  for (int b = t; b < NB; b += 256) {
    int h = hist[b];
    if (h > 0) atomicAdd(&bucketCount[b], h);
  }
}

// ---------------- exclusive scan of counts (1 block, generic NB) ------------
__global__ __launch_bounds__(1024) void bucket_scan_kernel(
    const int* __restrict__ bucketCount, int* __restrict__ bucketStart,
    int* __restrict__ gCursor, int NB) {
  __shared__ int s[1024];
  int t = threadIdx.x;
  int K = (NB + 1023) >> 10;
  int b0 = t * K;
  int local = 0;
  for (int j = 0; j < K; ++j) {
    int b = b0 + j;
    if (b < NB) local += bucketCount[b];
  }
  int acc = local;
  s[t] = local;
  __syncthreads();
  for (int off = 1; off < 1024; off <<= 1) {
    int u = (t >= off) ? s[t - off] : 0;
    __syncthreads();
    acc += u;
    s[t] = acc;
    __syncthreads();
  }
  int run = acc - local;  // exclusive prefix of this thread's chunk
  for (int j = 0; j < K; ++j) {
    int b = b0 + j;
    if (b < NB) {
      bucketStart[b] = run;
      gCursor[b] = run;
      run += bucketCount[b];
    }
  }
}

// ---------------- partition: LDS tile-sort, then coalesced write ------------
__global__ __launch_bounds__(PTHREADS) void partition_kernel(
    const int* __restrict__ pt_src, const int* __restrict__ pt_dst,
    const int* __restrict__ tp_src, const int* __restrict__ tp_dst,
    int* __restrict__ gCursor, uint32_t* __restrict__ pk,
    int E, int NP, int NB) {
  __shared__ uint64_t buf[PTI];    // 64 KB sorted staging
  __shared__ int hist[MAXNB];
  __shared__ int lstart[MAXNB];
  __shared__ int gbase[MAXNB];
  __shared__ int cur[MAXNB];
  __shared__ int sc[PTHREADS];
  int t = threadIdx.x;
  long total = 2L * E;
  long e0 = (long)blockIdx.x * PTI;
  long rem = total - e0;
  int cnt = (rem < (long)PTI) ? (int)rem : PTI;

  for (int j = t; j < NB; j += PTHREADS) hist[j] = 0;
  __syncthreads();

  int bj[EPT];
  uint32_t pkj[EPT];
#pragma unroll
  for (int j = 0; j < EPT; ++j) {
    int i = j * PTHREADS + t;
    bj[j] = -1;
    if (i < cnt) {
      long e = e0 + i;
      int dstG, src;
      if (e < E) {
        dstG = NP + __builtin_nontemporal_load(&pt_dst[e]);
        src = __builtin_nontemporal_load(&pt_src[e]);
      } else {
        dstG = __builtin_nontemporal_load(&tp_dst[e - E]);
        src = NP + __builtin_nontemporal_load(&tp_src[e - E]);
      }
      int b = dstG >> BNSHIFT;
      bj[j] = b;
      pkj[j] = ((uint32_t)(dstG & (BN - 1)) << 20) | (uint32_t)src;
      atomicAdd(&hist[b], 1);
    }
  }
  __syncthreads();

  // inclusive scan of hist[0..NB) across PTHREADS slots (NB <= PTHREADS)
  int h = (t < NB) ? hist[t] : 0;
  int acc = h;
  sc[t] = h;
  __syncthreads();
  for (int off = 1; off < PTHREADS; off <<= 1) {
    int u = (t >= off) ? sc[t - off] : 0;
    __syncthreads();
    acc += u;
    sc[t] = acc;
    __syncthreads();
  }
  if (t < NB) {
    int ls = acc - h;  // exclusive prefix
    lstart[t] = ls;
    cur[t] = ls;
    gbase[t] = (h > 0) ? atomicAdd(&gCursor[t], h) : 0;
  }
  __syncthreads();

  // scatter into LDS, sorted by bucket; attach final global position
#pragma unroll
  for (int j = 0; j < EPT; ++j) {
    int b = bj[j];
    if (b >= 0) {
      int pos = atomicAdd(&cur[b], 1);
      int gpos = gbase[b] + (pos - lstart[b]);
      buf[pos] = ((uint64_t)(uint32_t)gpos << 32) | (uint64_t)pkj[j];
    }
  }
  __syncthreads();

  // coalesced drain: consecutive lanes hit consecutive slots within runs
  for (int i = t; i < cnt; i += PTHREADS) {
    uint64_t e = buf[i];
    pk[(uint32_t)(e >> 32)] = (uint32_t)e;
  }
}

// ---------------- per-bucket counting sort -> node-grouped CSR --------------
// Key = (dl, src>>SSH): per-node cols grouped by ascending source slice.
__global__ __launch_bounds__(1024) void local_csr_kernel(
    const int* __restrict__ bucketStart, const int* __restrict__ bucketCount,
    const uint32_t* __restrict__ pk, int* __restrict__ rowptr,
    int* __restrict__ col, int N, int TEtotal) {
  __shared__ int hist[BINS];   // 64 KB: counts -> exclusive prefixes -> cursors
  __shared__ int ssum[1024];
  int t = threadIdx.x;
  int b = blockIdx.x;
  for (int j = t; j < BINS; j += 1024) hist[j] = 0;
  __syncthreads();
  int beg = bucketStart[b], num = bucketCount[b];
  for (int i = t; i < num; i += 1024) {
    uint32_t w = pk[beg + i];
    int bin = (int)(((w >> 20) << 4) | ((w & 0xFFFFFu) >> SSH));
    atomicAdd(&hist[bin], 1);
  }
  __syncthreads();
  // scan 16384 bins: 16 serial per thread (one node) + 1024-wide block scan
  int b0 = t * 16;
  int local = 0;
#pragma unroll
  for (int j = 0; j < 16; ++j) local += hist[b0 + j];
  int acc = local;
  ssum[t] = local;
  __syncthreads();
  for (int off = 1; off < 1024; off <<= 1) {
    int u = (t >= off) ? ssum[t - off] : 0;
    __syncthreads();
    acc += u;
    ssum[t] = acc;
    __syncthreads();
  }
  int run = acc - local;  // exclusive prefix of this thread's node
  int node0 = (b << BNSHIFT) + t;
  if (node0 < N) rowptr[node0] = beg + run;
#pragma unroll
  for (int j = 0; j < 16; ++j) {
    int h = hist[b0 + j];
    hist[b0 + j] = run;
    run += h;
  }
  __syncthreads();
  for (int i = t; i < num; i += 1024) {
    uint32_t w = pk[beg + i];
    int bin = (int)(((w >> 20) << 4) | ((w & 0xFFFFFu) >> SSH));
    int pos = atomicAdd(&hist[bin], 1);
    col[beg + pos] = (int)(w & 0xFFFFFu);
  }
  if (b == 0 && t == 0) rowptr[N] = TEtotal;
}

// ---------------- pull aggregation: agg[n] = bf16(mean of src rows) ---------
// 8 lanes per node (8 nodes/wave), lane handles 8 dims via one uint4 (16 B).
__global__ __launch_bounds__(256) void pull_kernel(
    const int* __restrict__ rowptr, const int* __restrict__ col,
    const uint16_t* __restrict__ base, uint16_t* __restrict__ agg, int N) {
  int node = blockIdx.x * 32 + (threadIdx.x >> 3);
  int c = threadIdx.x & 7;  // dims 8c..8c+7
  if (node >= N) return;
  int beg = rowptr[node], end = rowptr[node + 1];
  float s[8] = {0, 0, 0, 0, 0, 0, 0, 0};
  const uint16_t* bp = base + c * 8;
  int i = beg;
  for (; i + 4 <= end; i += 4) {
    int c0 = col[i], c1 = col[i + 1], c2 = col[i + 2], c3 = col[i + 3];
    uint4 v0 = *(const uint4*)(bp + (size_t)c0 * 64);
    uint4 v1 = *(const uint4*)(bp + (size_t)c1 * 64);
    uint4 v2 = *(const uint4*)(bp + (size_t)c2 * 64);
    uint4 v3 = *(const uint4*)(bp + (size_t)c3 * 64);
    acc8(s, v0); acc8(s, v1); acc8(s, v2); acc8(s, v3);
  }
  for (; i < end; ++i)
    acc8(s, *(const uint4*)(bp + (size_t)col[i] * 64));
  int deg = end - beg;
  float inv = 1.0f / (float)(deg > 1 ? deg : 1);
  union { uint16_t h[8]; uint4 v; } o;
#pragma unroll
  for (int j = 0; j < 8; ++j) o.h[j] = f2b(s[j] * inv);
  *(uint4*)(agg + (size_t)node * 64 + c * 8) = o.v;
}

// ---------------- fused transform: xout = relu(x@Wroot + agg@Wrel + b) ------
// Wave-private LDS staging of the relu'd tile -> all epilogue global accesses
// are full-width vectors (f32x4 emb, uint4 x1, uint4 store). Bit-exact.
// FUSE=true (layer 1): writes S = emb + x + relu(...) (sum pass fused).
template <bool FUSE>
__global__ __launch_bounds__(256) void transform_kernel(
    const uint16_t* __restrict__ xpl, const uint16_t* __restrict__ xtr,
    const uint16_t* __restrict__ agg,
    const float* __restrict__ Wroot,
    const float* __restrict__ WrelP, const float* __restrict__ WrelT,
    const float* __restrict__ biasrow,
    const float* __restrict__ embP, const float* __restrict__ embT,
    uint16_t* __restrict__ xout, int NP, int NT, int BP) {
  __shared__ float tile[4][16][68];   // wave-private 16x64 (+4 pad) staging
  int wave = threadIdx.x >> 6;
  int lane = threadIdx.x & 63;
  int m = lane & 15, q = lane >> 4;   // MFMA roles
  int g = lane >> 3, c = lane & 7;    // epilogue row roles
  float (*tp)[68] = tile[wave];

  int wl, nw, ntiles, nodeBase;
  const uint16_t* xbase;
  const float* Wrel;
  const float* embBase;
  if ((int)blockIdx.x < BP) {
    wl = blockIdx.x * 4 + wave; nw = BP * 4; ntiles = NP / 16;
    xbase = xpl; Wrel = WrelP; nodeBase = 0; embBase = embP;
  } else {
    wl = (blockIdx.x - BP) * 4 + wave; nw = (gridDim.x - BP) * 4; ntiles = NT / 16;
    xbase = xtr; Wrel = WrelT; nodeBase = NP; embBase = embT;
  }

  // B fragments: B[k][n], lane n=16*ct+m, elems k=32*kc+8*q+i
  bf16x8 br[2][4], bl[2][4];
  for (int kc = 0; kc < 2; ++kc)
    for (int ct = 0; ct < 4; ++ct) {
      int n = 16 * ct + m;
      int k0 = 32 * kc + 8 * q;
      bf16x8 t0, t1;
      for (int i = 0; i < 8; ++i) {
        t0[i] = (short)f2b(Wroot[(size_t)(k0 + i) * 64 + n]);
        t1[i] = (short)f2b(Wrel[(size_t)(k0 + i) * 64 + n]);
      }
      br[kc][ct] = t0;
      bl[kc][ct] = t1;
    }
  float bv[4];
  for (int ct = 0; ct < 4; ++ct) bv[ct] = biasrow[16 * ct + m];

  for (int t = wl; t < ntiles; t += nw) {
    int rowLocal = t * 16 + m;  // A row: m = lane&15
    int nodeG = nodeBase + rowLocal;
    const uint16_t* xrow = xbase + (size_t)rowLocal * 64;
    bf16x8 ax0 = *(const bf16x8*)(xrow + 8 * q);
    bf16x8 ax1 = *(const bf16x8*)(xrow + 32 + 8 * q);

    const uint16_t* arow = agg + (size_t)nodeG * 64;
    bf16x8 aa0 = *(const bf16x8*)(arow + 8 * q);
    bf16x8 aa1 = *(const bf16x8*)(arow + 32 + 8 * q);

    f32x4 acc[4];
#pragma unroll
    for (int ct = 0; ct < 4; ++ct) acc[ct] = (f32x4){bv[ct], bv[ct], bv[ct], bv[ct]};
#pragma unroll
    for (int ct = 0; ct < 4; ++ct) {
      acc[ct] = __builtin_amdgcn_mfma_f32_16x16x32_bf16(ax0, br[0][ct], acc[ct], 0, 0, 0);
      acc[ct] = __builtin_amdgcn_mfma_f32_16x16x32_bf16(ax1, br[1][ct], acc[ct], 0, 0, 0);
      acc[ct] = __builtin_amdgcn_mfma_f32_16x16x32_bf16(aa0, bl[0][ct], acc[ct], 0, 0, 0);
      acc[ct] = __builtin_amdgcn_mfma_f32_16x16x32_bf16(aa1, bl[1][ct], acc[ct], 0, 0, 0);
    }
    // stage relu'd D tile: row = 4*q + r, col = 16*ct + m
#pragma unroll
    for (int ct = 0; ct < 4; ++ct)
#pragma unroll
      for (int r = 0; r < 4; ++r) {
        float v = acc[ct][r];
        tp[4 * q + r][16 * ct + m] = v > 0.0f ? v : 0.0f;
      }
    // vector epilogue: lane handles rows {g, g+8}, dims [8c, 8c+8)
    int localRow0 = t * 16;
    int nodeRow0 = nodeBase + localRow0;
#pragma unroll
    for (int rr = 0; rr < 2; ++rr) {
      int row = g + rr * 8;
      f32x4 va = *(const f32x4*)&tp[row][8 * c];
      f32x4 vb = *(const f32x4*)&tp[row][8 * c + 4];
      union { uint16_t h[8]; uint4 v; } o;
      if (FUSE) {
        const float* erow = embBase + (size_t)(localRow0 + row) * 64 + 8 * c;
        f32x4 ea = *(const f32x4*)erow;
        f32x4 eb = *(const f32x4*)(erow + 4);
        uint4 xv = *(const uint4*)(xbase + (size_t)(localRow0 + row) * 64 + 8 * c);
        o.h[0] = f2b(ea.x + b2f_lo(xv.x) + va.x);
        o.h[1] = f2b(ea.y + b2f_hi(xv.x) + va.y);
        o.h[2] = f2b(ea.z + b2f_lo(xv.y) + va.z);
        o.h[3] = f2b(ea.w + b2f_hi(xv.y) + va.w);
        o.h[4] = f2b(eb.x + b2f_lo(xv.z) + vb.x);
        o.h[5] = f2b(eb.y + b2f_hi(xv.z) + vb.y);
        o.h[6] = f2b(eb.z + b2f_lo(xv.w) + vb.z);
        o.h[7] = f2b(eb.w + b2f_hi(xv.w) + vb.w);
      } else {
        o.h[0] = f2b(va.x); o.h[1] = f2b(va.y);
        o.h[2] = f2b(va.z); o.h[3] = f2b(va.w);
        o.h[4] = f2b(vb.x); o.h[5] = f2b(vb.y);
        o.h[6] = f2b(vb.z); o.h[7] = f2b(vb.w);
      }
      *(uint4*)(xout + (size_t)(nodeRow0 + row) * 64 + 8 * c) = o.v;
    }
  }
}

// ---------------- link scores: (1/9) * dot(S_p, S_t) ------------------------
// 8 lanes per pair, 8 dims each via uint4 (16 B).
__global__ void score_kernel(const int* __restrict__ ell_pl,
                             const int* __restrict__ ell_tr,
                             const uint16_t* __restrict__ S,
                             float* __restrict__ out, int EP, int NP) {
  long g = (long)blockIdx.x * blockDim.x + threadIdx.x;
  long pair = g >> 3;
  int c = (int)(g & 7);
  if (pair >= EP) return;
  int p = __builtin_nontemporal_load(&ell_pl[pair]);
  int t = __builtin_nontemporal_load(&ell_tr[pair]);
  uint4 vp = *(const uint4*)(S + (size_t)p * 64 + c * 8);
  uint4 vt = *(const uint4*)(S + (size_t)(NP + t) * 64 + c * 8);
  float partial = b2f_lo(vp.x) * b2f_lo(vt.x) + b2f_hi(vp.x) * b2f_hi(vt.x)
                + b2f_lo(vp.y) * b2f_lo(vt.y) + b2f_hi(vp.y) * b2f_hi(vt.y)
                + b2f_lo(vp.z) * b2f_lo(vt.z) + b2f_hi(vp.z) * b2f_hi(vt.z)
                + b2f_lo(vp.w) * b2f_lo(vt.w) + b2f_hi(vp.w) * b2f_hi(vt.w);
  partial += __shfl_xor(partial, 1);
  partial += __shfl_xor(partial, 2);
  partial += __shfl_xor(partial, 4);
  if (c == 0) __builtin_nontemporal_store(partial * (1.0f / 9.0f), &out[pair]);
}

extern "C" void kernel_launch(void* const* d_in, const int* in_sizes, int n_in,
                              void* d_out, int out_size, void* d_ws, size_t ws_size,
                              hipStream_t stream) {
  const float* emb_pl = (const float*)d_in[0];
  const float* emb_tr = (const float*)d_in[1];
  const float* W_rel = (const float*)d_in[2];   // [L,2,64,64] f32
  const float* W_root = (const float*)d_in[3];  // [L,64,64] f32
  const float* bias = (const float*)d_in[4];    // [L,64] f32
  const int* pt_src = (const int*)d_in[7];
  const int* pt_dst = (const int*)d_in[8];
  const int* tp_src = (const int*)d_in[9];
  const int* tp_dst = (const int*)d_in[10];
  const int* ell_pl = (const int*)d_in[11];
  const int* ell_tr = (const int*)d_in[12];
  float* out = (float*)d_out;

  const int NP = in_sizes[5];
  const int NT = in_sizes[6];
  const int E = in_sizes[7];
  const int EP = in_sizes[11];
  const int N = NP + NT;
  const long TE = 2L * E;
  const int NB = (N + BN - 1) / BN;

  char* ws = (char*)d_ws;
  size_t off = 0;
  uint16_t* agg = (uint16_t*)(ws + off); off += (size_t)N * 64 * 2;   // bf16
  uint16_t* x1  = (uint16_t*)(ws + off); off += (size_t)N * 64 * 2;   // bf16
  uint16_t* xb0 = (uint16_t*)(ws + off); off += (size_t)N * 64 * 2;   // bf16 emb copy
  uint16_t* S   = (uint16_t*)(ws + off); off += (size_t)N * 64 * 2;   // node sums
  uint32_t* pk  = (uint32_t*)(ws + off); off += (size_t)TE * 4;
  int* col      = (int*)(ws + off);      off += (size_t)TE * 4;
  int* rowptr   = (int*)(ws + off);      off += (size_t)(N + 1) * 4;
  int* bucketCount = (int*)(ws + off);   off += (size_t)NB * 4;
  int* bucketStart = (int*)(ws + off);   off += (size_t)NB * 4;
  int* gCursor     = (int*)(ws + off);   off += (size_t)NB * 4;

  const int TB = 256;
  int cvtBlocks = (int)(((long)N * 64 / 8 + TB - 1) / TB);
  int pullBlocks = (N + 31) / 32;
  int scoreBlocks = (int)(((long)EP * 8 + TB - 1) / TB);
  int partBlocks = (int)((TE + PTI - 1) / PTI);
  const int BP = 256, GT = 1024;  // transform grid split

  // ---- bf16 embedding copy (used by pull0 + transform0) ----
  convert_kernel<<<cvtBlocks, TB, 0, stream>>>(emb_pl, emb_tr, xb0, NP, N);

  // ---- bucket build (once; reused by both layers) ----
  hipMemsetAsync(bucketCount, 0, (size_t)NB * 4, stream);
  bucket_hist_kernel<<<1024, TB, NB * 4, stream>>>(pt_dst, tp_dst, bucketCount,
                                                   E, NP, NB);
  bucket_scan_kernel<<<1, 1024, 0, stream>>>(bucketCount, bucketStart, gCursor, NB);
  partition_kernel<<<partBlocks, PTHREADS, 0, stream>>>(
      pt_src, pt_dst, tp_src, tp_dst, gCursor, pk, E, NP, NB);
  local_csr_kernel<<<NB, 1024, 0, stream>>>(bucketStart, bucketCount, pk,
                                            rowptr, col, N, (int)TE);

  // ---- layer 0 (x = bf16 embedding copy) ----
  pull_kernel<<<pullBlocks, TB, 0, stream>>>(rowptr, col, xb0, agg, N);
  transform_kernel<false><<<GT, TB, 0, stream>>>(
      xb0, xb0 + (size_t)NP * 64, agg, W_root + 0 * 4096, W_rel + 1 * 4096,
      W_rel + 0 * 4096, bias + 0, nullptr, nullptr, x1, NP, NT, BP);

  // ---- layer 1 (x = x1); epilogue fuses S = emb + x1 + relu(h2) ----
  pull_kernel<<<pullBlocks, TB, 0, stream>>>(rowptr, col, x1, agg, N);
  transform_kernel<true><<<GT, TB, 0, stream>>>(
      x1, x1 + (size_t)NP * 64, agg, W_root + 1 * 4096, W_rel + 3 * 4096,
      W_rel + 2 * 4096, bias + 64, emb_pl, emb_tr, S, NP, NT, BP);

  // ---- link scores ----
  score_kernel<<<scoreBlocks, TB, 0, stream>>>(ell_pl, ell_tr, S, out, EP, NP);
}

// Round 13
// 494.397 us; speedup vs baseline: 1.1001x; 1.0102x over previous
//
#include <hip/hip_runtime.h>
#include <stdint.h>

typedef __attribute__((ext_vector_type(8))) short bf16x8;
typedef __attribute__((ext_vector_type(4))) float f32x4;

#define BN 1024      // dst nodes per bucket (power of 2)
#define BNSHIFT 10
#define MAXNB 512    // supports N up to 512*1024
#define PTI 8192     // edges per partition tile
#define PTHREADS 1024
#define EPT (PTI / PTHREADS)   // 8
#define SL 16        // source slices per node (sorted ascending -> L2 sweep)
#define SSH 15       // slice = src >> SSH
#define BINS (BN * SL)
#define HB 1024      // histogram blocks (first in the fused grid)

static __device__ __forceinline__ float b2f_lo(uint32_t w) {
  union { uint32_t u; float f; } c; c.u = w << 16; return c.f;
}
static __device__ __forceinline__ float b2f_hi(uint32_t w) {
  union { uint32_t u; float f; } c; c.u = w & 0xffff0000u; return c.f;
}
static __device__ __forceinline__ uint16_t f2b(float f) {
  union { float f; uint32_t u; } c; c.f = f;
  return (uint16_t)((c.u + 0x7fffu + ((c.u >> 16) & 1u)) >> 16);
}
static __device__ __forceinline__ void acc8(float* s, uint4 v) {
  s[0] += b2f_lo(v.x); s[1] += b2f_hi(v.x);
  s[2] += b2f_lo(v.y); s[3] += b2f_hi(v.y);
  s[4] += b2f_lo(v.z); s[5] += b2f_hi(v.z);
  s[6] += b2f_lo(v.w); s[7] += b2f_hi(v.w);
}

// -------- fused: bucket histogram (blocks 0..HB) + fp32->bf16 convert -------
// Hist blocks come FIRST in the grid so they launch into a full machine and
// the 9.5K streaming convert blocks fill in behind them — both independent,
// one dispatch drain instead of two. (Round-11's version failed because 128
// hist blocks ran as a starved tail AFTER convert; fixed by ordering + 1024.)
__global__ __launch_bounds__(256) void convert_hist_kernel(
    const float* __restrict__ emb_pl, const float* __restrict__ emb_tr,
    uint16_t* __restrict__ xb,
    const int* __restrict__ pt_dst, const int* __restrict__ tp_dst,
    int* __restrict__ bucketCount,
    int NP, int N, int E, int NB) {
  __shared__ int hist[MAXNB];
  int t = threadIdx.x;
  if ((int)blockIdx.x < HB) {
    // ---- histogram role: int4-vectorized dst reads, LDS-merged ----
    for (int b = t; b < NB; b += 256) hist[b] = 0;
    __syncthreads();
    long q = E >> 2;          // int4 chunks per relation
    long total4 = 2 * q;
    long stride = (long)HB * 256;
    for (long i = (long)blockIdx.x * 256 + t; i < total4; i += stride) {
      int4 v;
      int base;
      if (i < q) { v = ((const int4*)pt_dst)[i]; base = NP; }
      else       { v = ((const int4*)tp_dst)[i - q]; base = 0; }
      atomicAdd(&hist[(base + v.x) >> BNSHIFT], 1);
      atomicAdd(&hist[(base + v.y) >> BNSHIFT], 1);
      atomicAdd(&hist[(base + v.z) >> BNSHIFT], 1);
      atomicAdd(&hist[(base + v.w) >> BNSHIFT], 1);
    }
    if (blockIdx.x == 0) {   // scalar tail (E % 4)
      for (int e = (int)(q << 2) + t; e < E; e += 256) {
        atomicAdd(&hist[(NP + pt_dst[e]) >> BNSHIFT], 1);
        atomicAdd(&hist[tp_dst[e] >> BNSHIFT], 1);
      }
    }
    __syncthreads();
    for (int b = t; b < NB; b += 256) {
      int h = hist[b];
      if (h > 0) atomicAdd(&bucketCount[b], h);
    }
  } else {
    // ---- convert role ----
    long g = (long)(blockIdx.x - HB) * 256 + t;
    long base8 = g * 8;
    long total = (long)N * 64;
    if (base8 >= total) return;
    long plEnd = (long)NP * 64;  // divisible by 8, no straddle
    const float* src = (base8 < plEnd) ? (emb_pl + base8) : (emb_tr + (base8 - plEnd));
    f32x4 a = *(const f32x4*)src;
    f32x4 b = *(const f32x4*)(src + 4);
    union { uint16_t h[8]; uint4 v; } o;
    o.h[0] = f2b(a.x); o.h[1] = f2b(a.y); o.h[2] = f2b(a.z); o.h[3] = f2b(a.w);
    o.h[4] = f2b(b.x); o.h[5] = f2b(b.y); o.h[6] = f2b(b.z); o.h[7] = f2b(b.w);
    *(uint4*)(xb + base8) = o.v;
  }
}

// ---------------- exclusive scan of counts (1 block, generic NB) ------------
__global__ __launch_bounds__(1024) void bucket_scan_kernel(
    const int* __restrict__ bucketCount, int* __restrict__ bucketStart,
    int* __restrict__ gCursor, int NB) {
  __shared__ int s[1024];
  int t = threadIdx.x;
  int K = (NB + 1023) >> 10;
  int b0 = t * K;
  int local = 0;
  for (int j = 0; j < K; ++j) {
    int b = b0 + j;
    if (b < NB) local += bucketCount[b];
  }
  int acc = local;
  s[t] = local;
  __syncthreads();
  for (int off = 1; off < 1024; off <<= 1) {
    int u = (t >= off) ? s[t - off] : 0;
    __syncthreads();
    acc += u;
    s[t] = acc;
    __syncthreads();
  }
  int run = acc - local;  // exclusive prefix of this thread's chunk
  for (int j = 0; j < K; ++j) {
    int b = b0 + j;
    if (b < NB) {
      bucketStart[b] = run;
      gCursor[b] = run;
      run += bucketCount[b];
    }
  }
}

// ---------------- partition: LDS tile-sort, then coalesced write ------------
__global__ __launch_bounds__(PTHREADS) void partition_kernel(
    const int* __restrict__ pt_src, const int* __restrict__ pt_dst,
    const int* __restrict__ tp_src, const int* __restrict__ tp_dst,
    int* __restrict__ gCursor, uint32_t* __restrict__ pk,
    int E, int NP, int NB) {
  __shared__ uint64_t buf[PTI];    // 64 KB sorted staging
  __shared__ int hist[MAXNB];
  __shared__ int lstart[MAXNB];
  __shared__ int gbase[MAXNB];
  __shared__ int cur[MAXNB];
  __shared__ int sc[PTHREADS];
  int t = threadIdx.x;
  long total = 2L * E;
  long e0 = (long)blockIdx.x * PTI;
  long rem = total - e0;
  int cnt = (rem < (long)PTI) ? (int)rem : PTI;

  for (int j = t; j < NB; j += PTHREADS) hist[j] = 0;
  __syncthreads();

  int bj[EPT];
  uint32_t pkj[EPT];
#pragma unroll
  for (int j = 0; j < EPT; ++j) {
    int i = j * PTHREADS + t;
    bj[j] = -1;
    if (i < cnt) {
      long e = e0 + i;
      int dstG, src;
      if (e < E) {
        dstG = NP + __builtin_nontemporal_load(&pt_dst[e]);
        src = __builtin_nontemporal_load(&pt_src[e]);
      } else {
        dstG = __builtin_nontemporal_load(&tp_dst[e - E]);
        src = NP + __builtin_nontemporal_load(&tp_src[e - E]);
      }
      int b = dstG >> BNSHIFT;
      bj[j] = b;
      pkj[j] = ((uint32_t)(dstG & (BN - 1)) << 20) | (uint32_t)src;
      atomicAdd(&hist[b], 1);
    }
  }
  __syncthreads();

  // inclusive scan of hist[0..NB) across PTHREADS slots (NB <= PTHREADS)
  int h = (t < NB) ? hist[t] : 0;
  int acc = h;
  sc[t] = h;
  __syncthreads();
  for (int off = 1; off < PTHREADS; off <<= 1) {
    int u = (t >= off) ? sc[t - off] : 0;
    __syncthreads();
    acc += u;
    sc[t] = acc;
    __syncthreads();
  }
  if (t < NB) {
    int ls = acc - h;  // exclusive prefix
    lstart[t] = ls;
    cur[t] = ls;
    gbase[t] = (h > 0) ? atomicAdd(&gCursor[t], h) : 0;
  }
  __syncthreads();

  // scatter into LDS, sorted by bucket; attach final global position
#pragma unroll
  for (int j = 0; j < EPT; ++j) {
    int b = bj[j];
    if (b >= 0) {
      int pos = atomicAdd(&cur[b], 1);
      int gpos = gbase[b] + (pos - lstart[b]);
      buf[pos] = ((uint64_t)(uint32_t)gpos << 32) | (uint64_t)pkj[j];
    }
  }
  __syncthreads();

  // coalesced drain: consecutive lanes hit consecutive slots within runs
  for (int i = t; i < cnt; i += PTHREADS) {
    uint64_t e = buf[i];
    pk[(uint32_t)(e >> 32)] = (uint32_t)e;
  }
}

// ---------------- per-bucket counting sort -> node-grouped CSR --------------
// Key = (dl, src>>SSH): per-node cols grouped by ascending source slice.
__global__ __launch_bounds__(1024) void local_csr_kernel(
    const int* __restrict__ bucketStart, const int* __restrict__ bucketCount,
    const uint32_t* __restrict__ pk, int* __restrict__ rowptr,
    int* __restrict__ col, int N, int TEtotal) {
  __shared__ int hist[BINS];   // 64 KB: counts -> exclusive prefixes -> cursors
  __shared__ int ssum[1024];
  int t = threadIdx.x;
  int b = blockIdx.x;
  for (int j = t; j < BINS; j += 1024) hist[j] = 0;
  __syncthreads();
  int beg = bucketStart[b], num = bucketCount[b];
  for (int i = t; i < num; i += 1024) {
    uint32_t w = pk[beg + i];
    int bin = (int)(((w >> 20) << 4) | ((w & 0xFFFFFu) >> SSH));
    atomicAdd(&hist[bin], 1);
  }
  __syncthreads();
  // scan 16384 bins: 16 serial per thread (one node) + 1024-wide block scan
  int b0 = t * 16;
  int local = 0;
#pragma unroll
  for (int j = 0; j < 16; ++j) local += hist[b0 + j];
  int acc = local;
  ssum[t] = local;
  __syncthreads();
  for (int off = 1; off < 1024; off <<= 1) {
    int u = (t >= off) ? ssum[t - off] : 0;
    __syncthreads();
    acc += u;
    ssum[t] = acc;
    __syncthreads();
  }
  int run = acc - local;  // exclusive prefix of this thread's node
  int node0 = (b << BNSHIFT) + t;
  if (node0 < N) rowptr[node0] = beg + run;
#pragma unroll
  for (int j = 0; j < 16; ++j) {
    int h = hist[b0 + j];
    hist[b0 + j] = run;
    run += h;
  }
  __syncthreads();
  for (int i = t; i < num; i += 1024) {
    uint32_t w = pk[beg + i];
    int bin = (int)(((w >> 20) << 4) | ((w & 0xFFFFFu) >> SSH));
    int pos = atomicAdd(&hist[bin], 1);
    col[beg + pos] = (int)(w & 0xFFFFFu);
  }
  if (b == 0 && t == 0) rowptr[N] = TEtotal;
}

// ---------------- pull aggregation: agg[n] = bf16(mean of src rows) ---------
// 8 lanes per node (8 nodes/wave), lane handles 8 dims via one uint4 (16 B).
__global__ __launch_bounds__(256) void pull_kernel(
    const int* __restrict__ rowptr, const int* __restrict__ col,
    const uint16_t* __restrict__ base, uint16_t* __restrict__ agg, int N) {
  int node = blockIdx.x * 32 + (threadIdx.x >> 3);
  int c = threadIdx.x & 7;  // dims 8c..8c+7
  if (node >= N) return;
  int beg = rowptr[node], end = rowptr[node + 1];
  float s[8] = {0, 0, 0, 0, 0, 0, 0, 0};
  const uint16_t* bp = base + c * 8;
  int i = beg;
  for (; i + 4 <= end; i += 4) {
    int c0 = col[i], c1 = col[i + 1], c2 = col[i + 2], c3 = col[i + 3];
    uint4 v0 = *(const uint4*)(bp + (size_t)c0 * 64);
    uint4 v1 = *(const uint4*)(bp + (size_t)c1 * 64);
    uint4 v2 = *(const uint4*)(bp + (size_t)c2 * 64);
    uint4 v3 = *(const uint4*)(bp + (size_t)c3 * 64);
    acc8(s, v0); acc8(s, v1); acc8(s, v2); acc8(s, v3);
  }
  for (; i < end; ++i)
    acc8(s, *(const uint4*)(bp + (size_t)col[i] * 64));
  int deg = end - beg;
  float inv = 1.0f / (float)(deg > 1 ? deg : 1);
  union { uint16_t h[8]; uint4 v; } o;
#pragma unroll
  for (int j = 0; j < 8; ++j) o.h[j] = f2b(s[j] * inv);
  *(uint4*)(agg + (size_t)node * 64 + c * 8) = o.v;
}

// ---------------- fused transform: xout = relu(x@Wroot + agg@Wrel + b) ------
// Wave-private LDS staging of the relu'd tile -> all epilogue global accesses
// are full-width vectors (f32x4 emb, uint4 x1, uint4 store). Bit-exact.
// FUSE=true (layer 1): writes S = emb + x + relu(...) (sum pass fused).
template <bool FUSE>
__global__ __launch_bounds__(256) void transform_kernel(
    const uint16_t* __restrict__ xpl, const uint16_t* __restrict__ xtr,
    const uint16_t* __restrict__ agg,
    const float* __restrict__ Wroot,
    const float* __restrict__ WrelP, const float* __restrict__ WrelT,
    const float* __restrict__ biasrow,
    const float* __restrict__ embP, const float* __restrict__ embT,
    uint16_t* __restrict__ xout, int NP, int NT, int BP) {
  __shared__ float tile[4][16][68];   // wave-private 16x64 (+4 pad) staging
  int wave = threadIdx.x >> 6;
  int lane = threadIdx.x & 63;
  int m = lane & 15, q = lane >> 4;   // MFMA roles
  int g = lane >> 3, c = lane & 7;    // epilogue row roles
  float (*tp)[68] = tile[wave];

  int wl, nw, ntiles, nodeBase;
  const uint16_t* xbase;
  const float* Wrel;
  const float* embBase;
  if ((int)blockIdx.x < BP) {
    wl = blockIdx.x * 4 + wave; nw = BP * 4; ntiles = NP / 16;
    xbase = xpl; Wrel = WrelP; nodeBase = 0; embBase = embP;
  } else {
    wl = (blockIdx.x - BP) * 4 + wave; nw = (gridDim.x - BP) * 4; ntiles = NT / 16;
    xbase = xtr; Wrel = WrelT; nodeBase = NP; embBase = embT;
  }

  // B fragments: B[k][n], lane n=16*ct+m, elems k=32*kc+8*q+i
  bf16x8 br[2][4], bl[2][4];
  for (int kc = 0; kc < 2; ++kc)
    for (int ct = 0; ct < 4; ++ct) {
      int n = 16 * ct + m;
      int k0 = 32 * kc + 8 * q;
      bf16x8 t0, t1;
      for (int i = 0; i < 8; ++i) {
        t0[i] = (short)f2b(Wroot[(size_t)(k0 + i) * 64 + n]);
        t1[i] = (short)f2b(Wrel[(size_t)(k0 + i) * 64 + n]);
      }
      br[kc][ct] = t0;
      bl[kc][ct] = t1;
    }
  float bv[4];
  for (int ct = 0; ct < 4; ++ct) bv[ct] = biasrow[16 * ct + m];

  for (int t = wl; t < ntiles; t += nw) {
    int rowLocal = t * 16 + m;  // A row: m = lane&15
    int nodeG = nodeBase + rowLocal;
    const uint16_t* xrow = xbase + (size_t)rowLocal * 64;
    bf16x8 ax0 = *(const bf16x8*)(xrow + 8 * q);
    bf16x8 ax1 = *(const bf16x8*)(xrow + 32 + 8 * q);

    const uint16_t* arow = agg + (size_t)nodeG * 64;
    bf16x8 aa0 = *(const bf16x8*)(arow + 8 * q);
    bf16x8 aa1 = *(const bf16x8*)(arow + 32 + 8 * q);

    f32x4 acc[4];
#pragma unroll
    for (int ct = 0; ct < 4; ++ct) acc[ct] = (f32x4){bv[ct], bv[ct], bv[ct], bv[ct]};
#pragma unroll
    for (int ct = 0; ct < 4; ++ct) {
      acc[ct] = __builtin_amdgcn_mfma_f32_16x16x32_bf16(ax0, br[0][ct], acc[ct], 0, 0, 0);
      acc[ct] = __builtin_amdgcn_mfma_f32_16x16x32_bf16(ax1, br[1][ct], acc[ct], 0, 0, 0);
      acc[ct] = __builtin_amdgcn_mfma_f32_16x16x32_bf16(aa0, bl[0][ct], acc[ct], 0, 0, 0);
      acc[ct] = __builtin_amdgcn_mfma_f32_16x16x32_bf16(aa1, bl[1][ct], acc[ct], 0, 0, 0);
    }
    // stage relu'd D tile: row = 4*q + r, col = 16*ct + m
#pragma unroll
    for (int ct = 0; ct < 4; ++ct)
#pragma unroll
      for (int r = 0; r < 4; ++r) {
        float v = acc[ct][r];
        tp[4 * q + r][16 * ct + m] = v > 0.0f ? v : 0.0f;
      }
    // vector epilogue: lane handles rows {g, g+8}, dims [8c, 8c+8)
    int localRow0 = t * 16;
    int nodeRow0 = nodeBase + localRow0;
#pragma unroll
    for (int rr = 0; rr < 2; ++rr) {
      int row = g + rr * 8;
      f32x4 va = *(const f32x4*)&tp[row][8 * c];
      f32x4 vb = *(const f32x4*)&tp[row][8 * c + 4];
      union { uint16_t h[8]; uint4 v; } o;
      if (FUSE) {
        const float* erow = embBase + (size_t)(localRow0 + row) * 64 + 8 * c;
        f32x4 ea = *(const f32x4*)erow;
        f32x4 eb = *(const f32x4*)(erow + 4);
        uint4 xv = *(const uint4*)(xbase + (size_t)(localRow0 + row) * 64 + 8 * c);
        o.h[0] = f2b(ea.x + b2f_lo(xv.x) + va.x);
        o.h[1] = f2b(ea.y + b2f_hi(xv.x) + va.y);
        o.h[2] = f2b(ea.z + b2f_lo(xv.y) + va.z);
        o.h[3] = f2b(ea.w + b2f_hi(xv.y) + va.w);
        o.h[4] = f2b(eb.x + b2f_lo(xv.z) + vb.x);
        o.h[5] = f2b(eb.y + b2f_hi(xv.z) + vb.y);
        o.h[6] = f2b(eb.z + b2f_lo(xv.w) + vb.z);
        o.h[7] = f2b(eb.w + b2f_hi(xv.w) + vb.w);
      } else {
        o.h[0] = f2b(va.x); o.h[1] = f2b(va.y);
        o.h[2] = f2b(va.z); o.h[3] = f2b(va.w);
        o.h[4] = f2b(vb.x); o.h[5] = f2b(vb.y);
        o.h[6] = f2b(vb.z); o.h[7] = f2b(vb.w);
      }
      *(uint4*)(xout + (size_t)(nodeRow0 + row) * 64 + 8 * c) = o.v;
    }
  }
}

// ---------------- link scores: (1/9) * dot(S_p, S_t) ------------------------
// 8 lanes per pair, 8 dims each via uint4 (16 B).
__global__ void score_kernel(const int* __restrict__ ell_pl,
                             const int* __restrict__ ell_tr,
                             const uint16_t* __restrict__ S,
                             float* __restrict__ out, int EP, int NP) {
  long g = (long)blockIdx.x * blockDim.x + threadIdx.x;
  long pair = g >> 3;
  int c = (int)(g & 7);
  if (pair >= EP) return;
  int p = __builtin_nontemporal_load(&ell_pl[pair]);
  int t = __builtin_nontemporal_load(&ell_tr[pair]);
  uint4 vp = *(const uint4*)(S + (size_t)p * 64 + c * 8);
  uint4 vt = *(const uint4*)(S + (size_t)(NP + t) * 64 + c * 8);
  float partial = b2f_lo(vp.x) * b2f_lo(vt.x) + b2f_hi(vp.x) * b2f_hi(vt.x)
                + b2f_lo(vp.y) * b2f_lo(vt.y) + b2f_hi(vp.y) * b2f_hi(vt.y)
                + b2f_lo(vp.z) * b2f_lo(vt.z) + b2f_hi(vp.z) * b2f_hi(vt.z)
                + b2f_lo(vp.w) * b2f_lo(vt.w) + b2f_hi(vp.w) * b2f_hi(vt.w);
  partial += __shfl_xor(partial, 1);
  partial += __shfl_xor(partial, 2);
  partial += __shfl_xor(partial, 4);
  if (c == 0) __builtin_nontemporal_store(partial * (1.0f / 9.0f), &out[pair]);
}

extern "C" void kernel_launch(void* const* d_in, const int* in_sizes, int n_in,
                              void* d_out, int out_size, void* d_ws, size_t ws_size,
                              hipStream_t stream) {
  const float* emb_pl = (const float*)d_in[0];
  const float* emb_tr = (const float*)d_in[1];
  const float* W_rel = (const float*)d_in[2];   // [L,2,64,64] f32
  const float* W_root = (const float*)d_in[3];  // [L,64,64] f32
  const float* bias = (const float*)d_in[4];    // [L,64] f32
  const int* pt_src = (const int*)d_in[7];
  const int* pt_dst = (const int*)d_in[8];
  const int* tp_src = (const int*)d_in[9];
  const int* tp_dst = (const int*)d_in[10];
  const int* ell_pl = (const int*)d_in[11];
  const int* ell_tr = (const int*)d_in[12];
  float* out = (float*)d_out;

  const int NP = in_sizes[5];
  const int NT = in_sizes[6];
  const int E = in_sizes[7];
  const int EP = in_sizes[11];
  const int N = NP + NT;
  const long TE = 2L * E;
  const int NB = (N + BN - 1) / BN;

  char* ws = (char*)d_ws;
  size_t off = 0;
  uint16_t* agg = (uint16_t*)(ws + off); off += (size_t)N * 64 * 2;   // bf16
  uint16_t* x1  = (uint16_t*)(ws + off); off += (size_t)N * 64 * 2;   // bf16
  uint16_t* xb0 = (uint16_t*)(ws + off); off += (size_t)N * 64 * 2;   // bf16 emb copy
  uint16_t* S   = (uint16_t*)(ws + off); off += (size_t)N * 64 * 2;   // node sums
  uint32_t* pk  = (uint32_t*)(ws + off); off += (size_t)TE * 4;
  int* col      = (int*)(ws + off);      off += (size_t)TE * 4;
  int* rowptr   = (int*)(ws + off);      off += (size_t)(N + 1) * 4;
  int* bucketCount = (int*)(ws + off);   off += (size_t)NB * 4;
  int* bucketStart = (int*)(ws + off);   off += (size_t)NB * 4;
  int* gCursor     = (int*)(ws + off);   off += (size_t)NB * 4;

  const int TB = 256;
  int cvtBlocks = (int)(((long)N * 64 / 8 + TB - 1) / TB);
  int pullBlocks = (N + 31) / 32;
  int scoreBlocks = (int)(((long)EP * 8 + TB - 1) / TB);
  int partBlocks = (int)((TE + PTI - 1) / PTI);
  const int BP = 256, GT = 1024;  // transform grid split

  // ---- zero counts, then fused hist-first convert+hist (one dispatch) ----
  hipMemsetAsync(bucketCount, 0, (size_t)NB * 4, stream);
  convert_hist_kernel<<<HB + cvtBlocks, TB, 0, stream>>>(
      emb_pl, emb_tr, xb0, pt_dst, tp_dst, bucketCount, NP, N, E, NB);

  // ---- bucket build (once; reused by both layers) ----
  bucket_scan_kernel<<<1, 1024, 0, stream>>>(bucketCount, bucketStart, gCursor, NB);
  partition_kernel<<<partBlocks, PTHREADS, 0, stream>>>(
      pt_src, pt_dst, tp_src, tp_dst, gCursor, pk, E, NP, NB);
  local_csr_kernel<<<NB, 1024, 0, stream>>>(bucketStart, bucketCount, pk,
                                            rowptr, col, N, (int)TE);

  // ---- layer 0 (x = bf16 embedding copy) ----
  pull_kernel<<<pullBlocks, TB, 0, stream>>>(rowptr, col, xb0, agg, N);
  transform_kernel<false><<<GT, TB, 0, stream>>>(
      xb0, xb0 + (size_t)NP * 64, agg, W_root + 0 * 4096, W_rel + 1 * 4096,
      W_rel + 0 * 4096, bias + 0, nullptr, nullptr, x1, NP, NT, BP);

  // ---- layer 1 (x = x1); epilogue fuses S = emb + x1 + relu(h2) ----
  pull_kernel<<<pullBlocks, TB, 0, stream>>>(rowptr, col, x1, agg, N);
  transform_kernel<true><<<GT, TB, 0, stream>>>(
      x1, x1 + (size_t)NP * 64, agg, W_root + 1 * 4096, W_rel + 3 * 4096,
      W_rel + 2 * 4096, bias + 64, emb_pl, emb_tr, S, NP, NT, BP);

  // ---- link scores ----
  score_kernel<<<scoreBlocks, TB, 0, stream>>>(ell_pl, ell_tr, S, out, EP, NP);
}